// Round 3
// baseline (6574.108 us; speedup 1.0000x reference)
//
#include <hip/hip_runtime.h>

#define NPIX (512 * 512)
#define BLK 256

#define TOTB (NPIX * 6)
#define TOTS (NPIX * 3)
#define TOTE (NPIX * 9)

// persistent mega-kernel geometry: 256 blocks x 1024 threads = 262144 = NPIX.
// 1 block/CU on 256 CUs -> co-residency guaranteed (VGPR capped at 128 via
// __launch_bounds__(1024,4), zero LDS) -> grid barrier cannot deadlock.
#define NBLK 256
#define NTHR 1024
#define NTOT (NBLK * NTHR)

typedef _Float16 h4 __attribute__((ext_vector_type(4)));

constexpr float ALPHA_B = 32.0f / 33.0f;   // 1/(1+2^-5)
constexpr float ALPHA_S = 0.8f;            // 1/(1+2^-2)
constexpr float BI_COMPAT = 10.0f;
constexpr float SP_COMPAT = 3.0f;

// 4-byte CSR entry: [31:18] = weight (14-bit fixed point, /16383), [17:0] = pixel id
__device__ __forceinline__ unsigned pack_ent(int n, float w) {
    float wc = fminf(fmaxf(w, 0.f), 1.f);
    unsigned iw = (unsigned)(wc * 16383.f + 0.5f);
    return (iw << 18) | (unsigned)n;
}
__device__ __forceinline__ int ent_pix(unsigned e) { return (int)(e & 0x3FFFFu); }
__device__ __forceinline__ float ent_w(unsigned e) {
    return (float)(e >> 18) * (1.0f / 16383.0f);
}

__device__ __forceinline__ float4 f4zero() { return make_float4(0.f, 0.f, 0.f, 0.f); }
__device__ __forceinline__ h4 h4zero() {
    h4 z; z.x = (_Float16)0.f; z.y = (_Float16)0.f; z.z = (_Float16)0.f; z.w = (_Float16)0.f;
    return z;
}

// ---------------- device-scope grid barrier (persistent kernel) ----------------
// Sense via monotonically increasing phase counter. Only thread 0 of each block
// does atomics; other waves wait at the hardware block barrier. __threadfence()
// (agent-scope fence: L2 writeback + invalidate) makes each XCD's writes visible
// at the fabric before the arrive, and invalidates stale lines after release.
__device__ __forceinline__ void gridbar(int* cnt, int* phs, int& lph) {
    __syncthreads();
    if (threadIdx.x == 0) {
        int ph = lph;
        __threadfence();  // release: flush this XCD's writes
        int old = __hip_atomic_fetch_add(cnt, 1, __ATOMIC_ACQ_REL, __HIP_MEMORY_SCOPE_AGENT);
        if (old == NBLK - 1) {
            __hip_atomic_store(cnt, 0, __ATOMIC_RELAXED, __HIP_MEMORY_SCOPE_AGENT);
            __hip_atomic_store(phs, ph + 1, __ATOMIC_RELEASE, __HIP_MEMORY_SCOPE_AGENT);
        } else {
            while (__hip_atomic_load(phs, __ATOMIC_ACQUIRE, __HIP_MEMORY_SCOPE_AGENT) < ph + 1)
                __builtin_amdgcn_s_sleep(2);
        }
        lph = ph + 1;
        __threadfence();  // acquire: invalidate stale L1/L2 lines
    }
    __syncthreads();
}

// ---------------- softmax init (fallback path) ----------------
__global__ void k_softmax_init(const float4* __restrict__ u, float4* __restrict__ Q) {
    int n = blockIdx.x * BLK + threadIdx.x;
    if (n >= NPIX) return;
    float4 uu = u[n];
    float l0 = -uu.x, l1 = -uu.y, l2 = -uu.z, l3 = -uu.w;
    float m = fmaxf(fmaxf(l0, l1), fmaxf(l2, l3));
    float e0 = expf(l0 - m), e1 = expf(l1 - m), e2 = expf(l2 - m), e3 = expf(l3 - m);
    float inv = 1.0f / (e0 + e1 + e2 + e3);
    Q[n] = make_float4(e0 * inv, e1 * inv, e2 * inv, e3 * inv);
}

// ---------------- fused linked-list build + softmax init ----------------
// ONE atomic per entry (atomicExch) — counts are implicit in the list.
__global__ void k_link_softmax(const int* __restrict__ osb, const int* __restrict__ oss,
                               int* __restrict__ head, int* __restrict__ next,
                               const float4* __restrict__ u, float4* __restrict__ Q,
                               int Vb) {
    int n = blockIdx.x * BLK + threadIdx.x;
    if (n >= NPIX) return;
    float4 uu = u[n];
    float l0 = -uu.x, l1 = -uu.y, l2 = -uu.z, l3 = -uu.w;
    float m = fmaxf(fmaxf(l0, l1), fmaxf(l2, l3));
    float e0 = expf(l0 - m), e1 = expf(l1 - m), e2 = expf(l2 - m), e3 = expf(l3 - m);
    float inv = 1.0f / (e0 + e1 + e2 + e3);
    Q[n] = make_float4(e0 * inv, e1 * inv, e2 * inv, e3 * inv);
#pragma unroll
    for (int r = 0; r < 6; r++) {
        int o = osb[n * 6 + r];
        int e = n * 6 + r;
        next[e] = atomicExch(&head[o], e);
    }
#pragma unroll
    for (int r = 0; r < 3; r++) {
        int o = Vb + oss[n * 3 + r];
        int e = TOTB + n * 3 + r;
        next[e] = atomicExch(&head[o], e);
    }
}

// ---------------- CSR compaction with block-level allocation ----------------
__global__ void k_compact(const int* __restrict__ head, const int* __restrict__ next,
                          const float* __restrict__ wsb, const float* __restrict__ wss,
                          unsigned* __restrict__ ent, int* __restrict__ start,
                          int* __restrict__ endv,
                          float* __restrict__ nB, float* __restrict__ nS,
                          int* __restrict__ cursor, int V, int Vb) {
    __shared__ int lds[BLK];
    __shared__ int sbase;
    int o = blockIdx.x * BLK + threadIdx.x;
    bool valid = o < V;
    int h = valid ? head[o] : -1;
    int len = 0;
    for (int e = h; e >= 0; e = next[e]) len++;
    lds[threadIdx.x] = len;
    __syncthreads();
    for (int off = 1; off < BLK; off <<= 1) {
        int t = ((int)threadIdx.x >= off) ? lds[threadIdx.x - off] : 0;
        __syncthreads();
        lds[threadIdx.x] += t;
        __syncthreads();
    }
    int incl = lds[threadIdx.x];
    if (threadIdx.x == BLK - 1) sbase = atomicAdd(cursor, incl);
    __syncthreads();
    if (!valid) return;
    int pos = sbase + incl - len;
    start[o] = pos;
    endv[o] = pos + len;
    float acc = 0.f;
    if (o < Vb) {
        for (int e = h; e >= 0; e = next[e]) {
            unsigned n = (unsigned)e / 6u;  // wsb is pixel-major: wsb[e] is the weight
            unsigned pe = pack_ent((int)n, wsb[e]);
            acc += ent_w(pe);
            ent[pos++] = pe;
        }
        nB[o] = acc;
    } else {
        for (int e = h; e >= 0; e = next[e]) {
            int ee = e - TOTB;
            unsigned pe = pack_ent(ee / 3, wss[ee]);
            acc += ent_w(pe);
            ent[pos++] = pe;
        }
        nS[o - Vb] = acc;
    }
}

// ---------------- mega-kernel phase helpers (grid-stride, NTOT threads) ----------------
__device__ __forceinline__ void blur1_g(const float* __restrict__ in, float* __restrict__ out,
                                        const int* __restrict__ bn, int M, int tid) {
    for (int i = tid; i <= M; i += NTOT) {
        if (i == 0) { out[0] = 0.f; continue; }
        int n1 = bn[(size_t)(i - 1) * 2 + 0];
        int n2 = bn[(size_t)(i - 1) * 2 + 1];
        out[i] = in[i] + 0.5f * (in[n1] + in[n2]);
    }
}

__device__ __forceinline__ void blur4h_g(const h4* __restrict__ in, h4* __restrict__ out,
                                         const int* __restrict__ bn, int M, int tid) {
    for (int i = tid; i <= M; i += NTOT) {
        if (i == 0) { out[0] = h4zero(); continue; }
        int n1 = bn[(size_t)(i - 1) * 2 + 0];
        int n2 = bn[(size_t)(i - 1) * 2 + 1];
        h4 a = in[i], b = in[n1], c = in[n2];
        h4 o;
        o.x = (_Float16)((float)a.x + 0.5f * ((float)b.x + (float)c.x));
        o.y = (_Float16)((float)a.y + 0.5f * ((float)b.y + (float)c.y));
        o.z = (_Float16)((float)a.z + 0.5f * ((float)b.z + (float)c.z));
        o.w = (_Float16)((float)a.w + 0.5f * ((float)b.w + (float)c.w));
        out[i] = o;
    }
}

// ---------------- persistent mega-kernel: norm chain + prescale + 10 iterations ----------------
__global__ __launch_bounds__(NTHR, 4) void k_mega(
    const float4* __restrict__ u,
    const unsigned* __restrict__ ent, const int* __restrict__ start,
    const int* __restrict__ endv,
    const float* __restrict__ wsb, const int* __restrict__ osb,
    const float* __restrict__ wss, const int* __restrict__ oss,
    const int* __restrict__ bnb, int Mb, const int* __restrict__ bns, int Ms,
    float* nAb, float* nBb, float* nAs, float* nBs,
    float* __restrict__ wsbp, float* __restrict__ wssp,
    h4* tAb, h4* tBb, h4* tAs, h4* tBs,
    float4* __restrict__ Q,
    int* barcnt, int* barphs, int Vb, int Vs)
{
    const int tid = blockIdx.x * NTHR + threadIdx.x;
    const int V = Vb + Vs;
    int lph = 0;

    // ---- normalizer blur chain (inputs nAb/nAs from k_compact) ----
    {
        float* a = nAb; float* b = nBb;
        float* as_ = nAs; float* bs_ = nBs;
        for (int j = 0; j < 3; j++) {
            blur1_g(a, b, bnb + (size_t)j * Mb * 2, Mb, tid);
            blur1_g(as_, bs_, bns + (size_t)j * Ms * 2, Ms, tid);
            gridbar(barcnt, barphs, lph);
            float* t = a; a = b; b = t;
            t = as_; as_ = bs_; bs_ = t;
        }
        for (int j = 3; j < 6; j++) {
            blur1_g(a, b, bnb + (size_t)j * Mb * 2, Mb, tid);
            gridbar(barcnt, barphs, lph);
            float* t = a; a = b; b = t;
        }
        // bilateral final in a, spatial final in as_ ; prescale slice weights
        for (int n = tid; n < NPIX; n += NTOT) {
            float sb = 0.f;
#pragma unroll
            for (int r = 0; r < 6; r++) sb += wsb[n * 6 + r] * a[osb[n * 6 + r]];
            float cb = BI_COMPAT * ALPHA_B / (ALPHA_B * sb + 1e-20f);
#pragma unroll
            for (int r = 0; r < 6; r++) wsbp[n * 6 + r] = wsb[n * 6 + r] * cb;
            float ss = 0.f;
#pragma unroll
            for (int r = 0; r < 3; r++) ss += wss[n * 3 + r] * as_[oss[n * 3 + r]];
            float cs = SP_COMPAT * ALPHA_S / (ALPHA_S * ss + 1e-20f);
#pragma unroll
            for (int r = 0; r < 3; r++) wssp[n * 3 + r] = wss[n * 3 + r] * cs;
        }
        gridbar(barcnt, barphs, lph);
    }

    // ---- 10 mean-field iterations ----
    for (int it = 0; it < 10; it++) {
        // gather (splat-transpose): vertex-parallel over concatenated CSR
        for (int i = tid; i < V; i += NTOT) {
            int s = start[i];
            int e = endv[i];
            float ax = 0.f, ay = 0.f, az = 0.f, aw = 0.f;
            for (int k = s; k < e; k++) {
                unsigned en = ent[k];
                float w = ent_w(en);
                float4 q = Q[ent_pix(en)];
                ax += w * q.x; ay += w * q.y; az += w * q.z; aw += w * q.w;
            }
            h4 h;
            h.x = (_Float16)ax; h.y = (_Float16)ay; h.z = (_Float16)az; h.w = (_Float16)aw;
            if (i < Vb) tAb[i] = h;
            else tAs[i - Vb] = h;
        }
        gridbar(barcnt, barphs, lph);

        h4* a = tAb; h4* b = tBb;
        h4* as_ = tAs; h4* bs_ = tBs;
        for (int j = 0; j < 3; j++) {
            blur4h_g(a, b, bnb + (size_t)j * Mb * 2, Mb, tid);
            blur4h_g(as_, bs_, bns + (size_t)j * Ms * 2, Ms, tid);
            gridbar(barcnt, barphs, lph);
            h4* t = a; a = b; b = t;
            t = as_; as_ = bs_; bs_ = t;
        }
        for (int j = 3; j < 6; j++) {
            blur4h_g(a, b, bnb + (size_t)j * Mb * 2, Mb, tid);
            gridbar(barcnt, barphs, lph);
            h4* t = a; a = b; b = t;
        }
        // bilateral final in a (= tAb), spatial final in as_ (= tBs)
        for (int n = tid; n < NPIX; n += NTOT) {
            float4 uu = u[n];
            float l0 = -uu.x, l1 = -uu.y, l2 = -uu.z, l3 = -uu.w;
#pragma unroll
            for (int r = 0; r < 6; r++) {
                float w = wsbp[n * 6 + r];
                h4 t = a[osb[n * 6 + r]];
                l0 += w * (float)t.x; l1 += w * (float)t.y;
                l2 += w * (float)t.z; l3 += w * (float)t.w;
            }
#pragma unroll
            for (int r = 0; r < 3; r++) {
                float w = wssp[n * 3 + r];
                h4 t = as_[oss[n * 3 + r]];
                l0 += w * (float)t.x; l1 += w * (float)t.y;
                l2 += w * (float)t.z; l3 += w * (float)t.w;
            }
            float m = fmaxf(fmaxf(l0, l1), fmaxf(l2, l3));
            float e0 = expf(l0 - m), e1 = expf(l1 - m), e2 = expf(l2 - m), e3 = expf(l3 - m);
            float inv = 1.0f / (e0 + e1 + e2 + e3);
            Q[n] = make_float4(e0 * inv, e1 * inv, e2 * inv, e3 * inv);
        }
        if (it < 9) gridbar(barcnt, barphs, lph);
    }
}

// ---------------- fallback (fp32 atomic splat path) ----------------
__global__ void k_blur1(const float* __restrict__ in, float* __restrict__ out,
                        const int* __restrict__ bn, int M) {
    int i = blockIdx.x * BLK + threadIdx.x;
    if (i > M) return;
    if (i == 0) { out[0] = 0.f; return; }
    int n1 = bn[(size_t)(i - 1) * 2 + 0];
    int n2 = bn[(size_t)(i - 1) * 2 + 1];
    out[i] = in[i] + 0.5f * (in[n1] + in[n2]);
}

template <int D1>
__global__ void k_splat1(const float* __restrict__ ws, const int* __restrict__ os,
                         float* __restrict__ table) {
    int n = blockIdx.x * BLK + threadIdx.x;
    if (n >= NPIX) return;
#pragma unroll
    for (int r = 0; r < D1; r++) atomicAdd(&table[os[n * D1 + r]], ws[n * D1 + r]);
}

template <int D1>
__global__ void k_splat4(const float4* __restrict__ Q, const float* __restrict__ ws,
                         const int* __restrict__ os, float* __restrict__ table) {
    int n = blockIdx.x * BLK + threadIdx.x;
    if (n >= NPIX) return;
    float4 q = Q[n];
#pragma unroll
    for (int r = 0; r < D1; r++) {
        float w = ws[n * D1 + r];
        int o = os[n * D1 + r];
        float* t = table + 4 * (size_t)o;
        atomicAdd(t + 0, q.x * w);
        atomicAdd(t + 1, q.y * w);
        atomicAdd(t + 2, q.z * w);
        atomicAdd(t + 3, q.w * w);
    }
}

__global__ void k_blur4(const float4* __restrict__ in, float4* __restrict__ out,
                        const int* __restrict__ bn, int M) {
    int i = blockIdx.x * BLK + threadIdx.x;
    if (i > M) return;
    if (i == 0) { out[0] = f4zero(); return; }
    int n1 = bn[(size_t)(i - 1) * 2 + 0];
    int n2 = bn[(size_t)(i - 1) * 2 + 1];
    float4 a = in[i], b = in[n1], c = in[n2];
    out[i] = make_float4(a.x + 0.5f * (b.x + c.x), a.y + 0.5f * (b.y + c.y),
                         a.z + 0.5f * (b.z + c.z), a.w + 0.5f * (b.w + c.w));
}

template <int D1>
__global__ void k_norm_slice(const float* __restrict__ table, const float* __restrict__ ws,
                             const int* __restrict__ os, float alpha,
                             float* __restrict__ inv_out) {
    int n = blockIdx.x * BLK + threadIdx.x;
    if (n >= NPIX) return;
    float s = 0.f;
#pragma unroll
    for (int r = 0; r < D1; r++) s += ws[n * D1 + r] * table[os[n * D1 + r]];
    inv_out[n] = 1.0f / (alpha * s + 1e-20f);
}

__global__ void k_slice_combine(const float4* __restrict__ u,
                                const float4* __restrict__ tb, const float* __restrict__ wsb,
                                const int* __restrict__ osb,
                                const float4* __restrict__ ts, const float* __restrict__ wss,
                                const int* __restrict__ oss,
                                const float* __restrict__ inv_nb,
                                const float* __restrict__ inv_ns,
                                float4* __restrict__ Qout) {
    int n = blockIdx.x * BLK + threadIdx.x;
    if (n >= NPIX) return;
    float4 ab = f4zero();
#pragma unroll
    for (int r = 0; r < 6; r++) {
        float w = wsb[n * 6 + r];
        float4 t = tb[osb[n * 6 + r]];
        ab.x += w * t.x; ab.y += w * t.y; ab.z += w * t.z; ab.w += w * t.w;
    }
    float4 as = f4zero();
#pragma unroll
    for (int r = 0; r < 3; r++) {
        float w = wss[n * 3 + r];
        float4 t = ts[oss[n * 3 + r]];
        as.x += w * t.x; as.y += w * t.y; as.z += w * t.z; as.w += w * t.w;
    }
    float cb = BI_COMPAT * ALPHA_B * inv_nb[n];
    float cs = SP_COMPAT * ALPHA_S * inv_ns[n];
    float4 uu = u[n];
    float l0 = -uu.x + cb * ab.x + cs * as.x;
    float l1 = -uu.y + cb * ab.y + cs * as.y;
    float l2 = -uu.z + cb * ab.z + cs * as.z;
    float l3 = -uu.w + cb * ab.w + cs * as.w;
    float m = fmaxf(fmaxf(l0, l1), fmaxf(l2, l3));
    float e0 = expf(l0 - m), e1 = expf(l1 - m), e2 = expf(l2 - m), e3 = expf(l3 - m);
    float inv = 1.0f / (e0 + e1 + e2 + e3);
    Qout[n] = make_float4(e0 * inv, e1 * inv, e2 * inv, e3 * inv);
}

extern "C" void kernel_launch(void* const* d_in, const int* in_sizes, int n_in,
                              void* d_out, int out_size, void* d_ws, size_t ws_size,
                              hipStream_t stream) {
    const float* unary = (const float*)d_in[0];
    const float* wsb   = (const float*)d_in[1];
    const int*   osb   = (const int*)d_in[2];
    const int*   bnb   = (const int*)d_in[3];
    const float* wss   = (const float*)d_in[5];
    const int*   oss   = (const int*)d_in[6];
    const int*   bns   = (const int*)d_in[7];
    const int Mb = in_sizes[3] / 12;   // bn_b is (6, Mb, 2)
    const int Ms = in_sizes[7] / 6;    // bn_s is (3, Ms, 2)
    const int Vb = Mb + 1, Vs = Ms + 1;
    const int V = Vb + Vs;

    float* Q = (float*)d_out;  // N x 4, final value IS the output

    char* p = (char*)d_ws;
    auto alloc = [&](size_t nbytes) -> void* {
        void* r = (void*)p;
        p += (nbytes + 15) & ~(size_t)15;
        return r;
    };
    h4*   tAb  = (h4*)alloc((size_t)Vb * 8);
    h4*   tBb  = (h4*)alloc((size_t)Vb * 8);
    h4*   tAs  = (h4*)alloc((size_t)Vs * 8);
    h4*   tBs  = (h4*)alloc((size_t)Vs * 8);
    float* nAb = (float*)alloc((size_t)Vb * 4);
    float* nBb = (float*)alloc((size_t)Vb * 4);
    float* nAs = (float*)alloc((size_t)Vs * 4);
    float* nBs = (float*)alloc((size_t)Vs * 4);
    // wsbp (6N floats) and wssp (3N floats) are contiguous (6N*4 is 16B-aligned);
    // the 9N-int `next` array aliases them: next is dead after k_compact, and
    // wsbp/wssp are first written inside k_mega (after k_compact completes).
    float* wsbp = (float*)alloc((size_t)NPIX * 6 * 4);
    float* wssp = (float*)alloc((size_t)NPIX * 3 * 4);
    int*   next = (int*)wsbp;
    int*  start = (int*)alloc((size_t)V * 4);
    int*  endv  = (int*)alloc((size_t)V * 4);
    int*  head  = (int*)alloc((size_t)V * 4);
    unsigned* ent = (unsigned*)alloc((size_t)TOTE * 4);
    int*  bar   = (int*)alloc(256);   // [0]=count (own line), [64]=phase
    size_t need = (size_t)(p - (char*)d_ws);
    bool use_gather = need <= ws_size;

    dim3 blk(BLK);
    dim3 gN((NPIX + BLK - 1) / BLK);
    dim3 gV((V + BLK - 1) / BLK);

    if (use_gather) {
        int* barcnt = bar;        // cache-line separated
        int* barphs = bar + 32;
        int* cursor = bar + 48;
        // ---- build CSR via linked-list inversion + self-allocating compaction ----
        hipMemsetAsync(head, 0xFF, (size_t)V * 4, stream);  // -1 sentinel
        hipMemsetAsync(bar, 0, 256, stream);                // barrier ctl + cursor
        k_link_softmax<<<gN, blk, 0, stream>>>(osb, oss, head, next,
                                               (const float4*)unary, (float4*)Q, Vb);
        k_compact<<<gV, blk, 0, stream>>>(head, next, wsb, wss, ent, start, endv,
                                          nAb, nAs, cursor, V, Vb);
        // ---- everything else in ONE persistent kernel ----
        k_mega<<<dim3(NBLK), dim3(NTHR), 0, stream>>>(
            (const float4*)unary, ent, start, endv,
            wsb, osb, wss, oss, bnb, Mb, bns, Ms,
            nAb, nBb, nAs, nBs, wsbp, wssp,
            tAb, tBb, tAs, tBs, (float4*)Q,
            barcnt, barphs, Vb, Vs);
    } else {
        // ---- fallback: fp32 atomic splat path ----
        char* q = (char*)d_ws;
        auto alloc2 = [&](size_t nbytes) -> void* {
            void* r = (void*)q;
            q += (nbytes + 15) & ~(size_t)15;
            return r;
        };
        float* fAb = (float*)alloc2((size_t)Vb * 4 * sizeof(float));
        float* fBb = (float*)alloc2((size_t)Vb * 4 * sizeof(float));
        float* fAs = (float*)alloc2((size_t)Vs * 4 * sizeof(float));
        float* fBs = (float*)alloc2((size_t)Vs * 4 * sizeof(float));
        float* inv_nb = (float*)alloc2(NPIX * sizeof(float));
        float* inv_ns = (float*)alloc2(NPIX * sizeof(float));
        dim3 gMb((Mb + 1 + BLK - 1) / BLK);
        dim3 gMs((Ms + 1 + BLK - 1) / BLK);

        hipMemsetAsync(fAb, 0, (size_t)Vb * sizeof(float), stream);
        k_splat1<6><<<gN, blk, 0, stream>>>(wsb, osb, fAb);
        {
            float* a = fAb; float* b = fBb;
            for (int j = 0; j < 6; j++) {
                k_blur1<<<gMb, blk, 0, stream>>>(a, b, bnb + (size_t)j * Mb * 2, Mb);
                float* t = a; a = b; b = t;
            }
            k_norm_slice<6><<<gN, blk, 0, stream>>>(a, wsb, osb, ALPHA_B, inv_nb);
        }
        hipMemsetAsync(fAs, 0, (size_t)Vs * sizeof(float), stream);
        k_splat1<3><<<gN, blk, 0, stream>>>(wss, oss, fAs);
        {
            float* a = fAs; float* b = fBs;
            for (int j = 0; j < 3; j++) {
                k_blur1<<<gMs, blk, 0, stream>>>(a, b, bns + (size_t)j * Ms * 2, Ms);
                float* t = a; a = b; b = t;
            }
            k_norm_slice<3><<<gN, blk, 0, stream>>>(a, wss, oss, ALPHA_S, inv_ns);
        }
        k_softmax_init<<<gN, blk, 0, stream>>>((const float4*)unary, (float4*)Q);
        for (int it = 0; it < 10; it++) {
            hipMemsetAsync(fAb, 0, (size_t)Vb * 4 * sizeof(float), stream);
            k_splat4<6><<<gN, blk, 0, stream>>>((const float4*)Q, wsb, osb, fAb);
            float* a = fAb; float* b = fBb;
            for (int j = 0; j < 6; j++) {
                k_blur4<<<gMb, blk, 0, stream>>>((const float4*)a, (float4*)b,
                                                 bnb + (size_t)j * Mb * 2, Mb);
                float* t = a; a = b; b = t;
            }
            float* finb = a;
            hipMemsetAsync(fAs, 0, (size_t)Vs * 4 * sizeof(float), stream);
            k_splat4<3><<<gN, blk, 0, stream>>>((const float4*)Q, wss, oss, fAs);
            float* as_ = fAs; float* bs_ = fBs;
            for (int j = 0; j < 3; j++) {
                k_blur4<<<gMs, blk, 0, stream>>>((const float4*)as_, (float4*)bs_,
                                                 bns + (size_t)j * Ms * 2, Ms);
                float* t = as_; as_ = bs_; bs_ = t;
            }
            float* fins = as_;
            k_slice_combine<<<gN, blk, 0, stream>>>((const float4*)unary,
                                                    (const float4*)finb, wsb, osb,
                                                    (const float4*)fins, wss, oss,
                                                    inv_nb, inv_ns, (float4*)Q);
        }
    }
}

// Round 4
// 965.666 us; speedup vs baseline: 6.8078x; 6.8078x over previous
//
#include <hip/hip_runtime.h>

#define NPIX (512 * 512)
#define BLK 256

#define TOTB (NPIX * 6)
#define TOTS (NPIX * 3)
#define TOTE (NPIX * 9)

typedef _Float16 h4 __attribute__((ext_vector_type(4)));

constexpr float ALPHA_B = 32.0f / 33.0f;   // 1/(1+2^-5)
constexpr float ALPHA_S = 0.8f;            // 1/(1+2^-2)
constexpr float BI_COMPAT = 10.0f;
constexpr float SP_COMPAT = 3.0f;

// 4-byte CSR entry: [31:18] = weight (14-bit fixed point, /16383), [17:0] = pixel id
__device__ __forceinline__ unsigned pack_ent(int n, float w) {
    float wc = fminf(fmaxf(w, 0.f), 1.f);
    unsigned iw = (unsigned)(wc * 16383.f + 0.5f);
    return (iw << 18) | (unsigned)n;
}
__device__ __forceinline__ int ent_pix(unsigned e) { return (int)(e & 0x3FFFFu); }
__device__ __forceinline__ float ent_w(unsigned e) {
    return (float)(e >> 18) * (1.0f / 16383.0f);
}

__device__ __forceinline__ float4 f4zero() { return make_float4(0.f, 0.f, 0.f, 0.f); }
__device__ __forceinline__ h4 h4zero() {
    h4 z; z.x = (_Float16)0.f; z.y = (_Float16)0.f; z.z = (_Float16)0.f; z.w = (_Float16)0.f;
    return z;
}
__device__ __forceinline__ h4 blurmix(h4 a, h4 b, h4 c) {
    h4 o;
    o.x = (_Float16)((float)a.x + 0.5f * ((float)b.x + (float)c.x));
    o.y = (_Float16)((float)a.y + 0.5f * ((float)b.y + (float)c.y));
    o.z = (_Float16)((float)a.z + 0.5f * ((float)b.z + (float)c.z));
    o.w = (_Float16)((float)a.w + 0.5f * ((float)b.w + (float)c.w));
    return o;
}

// ---------------- softmax init (fallback path) ----------------
__global__ void k_softmax_init(const float4* __restrict__ u, float4* __restrict__ Q) {
    int n = blockIdx.x * BLK + threadIdx.x;
    if (n >= NPIX) return;
    float4 uu = u[n];
    float l0 = -uu.x, l1 = -uu.y, l2 = -uu.z, l3 = -uu.w;
    float m = fmaxf(fmaxf(l0, l1), fmaxf(l2, l3));
    float e0 = expf(l0 - m), e1 = expf(l1 - m), e2 = expf(l2 - m), e3 = expf(l3 - m);
    float inv = 1.0f / (e0 + e1 + e2 + e3);
    Q[n] = make_float4(e0 * inv, e1 * inv, e2 * inv, e3 * inv);
}

// ---------------- fused linked-list build + softmax init ----------------
// ONE atomic per entry (atomicExch) — counts are implicit in the list.
__global__ void k_link_softmax(const int* __restrict__ osb, const int* __restrict__ oss,
                               int* __restrict__ head, int* __restrict__ next,
                               const float4* __restrict__ u, float4* __restrict__ Q,
                               int Vb) {
    int n = blockIdx.x * BLK + threadIdx.x;
    if (n >= NPIX) return;
    float4 uu = u[n];
    float l0 = -uu.x, l1 = -uu.y, l2 = -uu.z, l3 = -uu.w;
    float m = fmaxf(fmaxf(l0, l1), fmaxf(l2, l3));
    float e0 = expf(l0 - m), e1 = expf(l1 - m), e2 = expf(l2 - m), e3 = expf(l3 - m);
    float inv = 1.0f / (e0 + e1 + e2 + e3);
    Q[n] = make_float4(e0 * inv, e1 * inv, e2 * inv, e3 * inv);
#pragma unroll
    for (int r = 0; r < 6; r++) {
        int o = osb[n * 6 + r];
        int e = n * 6 + r;
        next[e] = atomicExch(&head[o], e);
    }
#pragma unroll
    for (int r = 0; r < 3; r++) {
        int o = Vb + oss[n * 3 + r];
        int e = TOTB + n * 3 + r;
        next[e] = atomicExch(&head[o], e);
    }
}

// ---------------- CSR compaction with block-level allocation ----------------
__global__ void k_compact(const int* __restrict__ head, const int* __restrict__ next,
                          const float* __restrict__ wsb, const float* __restrict__ wss,
                          unsigned* __restrict__ ent, int* __restrict__ start,
                          int* __restrict__ endv,
                          float* __restrict__ nB, float* __restrict__ nS,
                          int* __restrict__ cursor, int V, int Vb) {
    __shared__ int lds[BLK];
    __shared__ int sbase;
    int o = blockIdx.x * BLK + threadIdx.x;
    bool valid = o < V;
    int h = valid ? head[o] : -1;
    int len = 0;
    for (int e = h; e >= 0; e = next[e]) len++;
    lds[threadIdx.x] = len;
    __syncthreads();
    for (int off = 1; off < BLK; off <<= 1) {
        int t = ((int)threadIdx.x >= off) ? lds[threadIdx.x - off] : 0;
        __syncthreads();
        lds[threadIdx.x] += t;
        __syncthreads();
    }
    int incl = lds[threadIdx.x];
    if (threadIdx.x == BLK - 1) sbase = atomicAdd(cursor, incl);
    __syncthreads();
    if (!valid) return;
    int pos = sbase + incl - len;
    start[o] = pos;
    endv[o] = pos + len;
    float acc = 0.f;
    if (o < Vb) {
        for (int e = h; e >= 0; e = next[e]) {
            unsigned n = (unsigned)e / 6u;  // wsb is pixel-major: wsb[e] is the weight
            unsigned pe = pack_ent((int)n, wsb[e]);
            acc += ent_w(pe);
            ent[pos++] = pe;
        }
        nB[o] = acc;
    } else {
        for (int e = h; e >= 0; e = next[e]) {
            int ee = e - TOTB;
            unsigned pe = pack_ent(ee / 3, wss[ee]);
            acc += ent_w(pe);
            ent[pos++] = pe;
        }
        nS[o - Vb] = acc;
    }
}

// ---------------- gather-based splat (single concatenated CSR) ----------------
__global__ void k_gather4h_both(const unsigned* __restrict__ ent, const int* __restrict__ start,
                                const int* __restrict__ endv, int V, int Vb,
                                h4* __restrict__ tB, h4* __restrict__ tS,
                                const float4* __restrict__ Q) {
    int i = blockIdx.x * BLK + threadIdx.x;
    if (i >= V) return;
    int s = start[i];
    int e = endv[i];
    float ax = 0.f, ay = 0.f, az = 0.f, aw = 0.f;
    for (int k = s; k < e; k++) {
        unsigned en = ent[k];
        float w = ent_w(en);
        float4 q = Q[ent_pix(en)];
        ax += w * q.x; ay += w * q.y; az += w * q.z; aw += w * q.w;
    }
    h4 h;
    h.x = (_Float16)ax; h.y = (_Float16)ay; h.z = (_Float16)az; h.w = (_Float16)aw;
    if (i < Vb) tB[i] = h;
    else tS[i - Vb] = h;
}

// ---------------- 2-vertices-per-thread blur (ILP for scattered loads) ----------------
// Pair p covers vertices i0=2p, i1=2p+1 of table [0..M]. Identical arithmetic/order
// to the 1-per-thread version; vertex 0 is the zero sentinel.
__device__ __forceinline__ void blur4h_two(const h4* __restrict__ in, h4* __restrict__ out,
                                           const int* __restrict__ bn, int M, int p) {
    int i0 = p * 2, i1 = i0 + 1;
    if (i0 > M) return;
    bool has1 = (i1 <= M);
    int n10 = 0, n20 = 0, n11 = 0, n21 = 0;
    if (i0 > 0) { int2 nb = *(const int2*)&bn[(size_t)(i0 - 1) * 2]; n10 = nb.x; n20 = nb.y; }
    if (has1)   { int2 nb = *(const int2*)&bn[(size_t)(i1 - 1) * 2]; n11 = nb.x; n21 = nb.y; }
    // issue all scattered loads before any use
    h4 a0 = in[i0];
    h4 b0 = in[n10], c0 = in[n20];
    h4 a1 = in[has1 ? i1 : 0];
    h4 b1 = in[n11], c1 = in[n21];
    out[i0] = (i0 == 0) ? h4zero() : blurmix(a0, b0, c0);
    if (has1) out[i1] = blurmix(a1, b1, c1);
}

__device__ __forceinline__ void blur1_two(const float* __restrict__ in, float* __restrict__ out,
                                          const int* __restrict__ bn, int M, int p) {
    int i0 = p * 2, i1 = i0 + 1;
    if (i0 > M) return;
    bool has1 = (i1 <= M);
    int n10 = 0, n20 = 0, n11 = 0, n21 = 0;
    if (i0 > 0) { int2 nb = *(const int2*)&bn[(size_t)(i0 - 1) * 2]; n10 = nb.x; n20 = nb.y; }
    if (has1)   { int2 nb = *(const int2*)&bn[(size_t)(i1 - 1) * 2]; n11 = nb.x; n21 = nb.y; }
    float a0 = in[i0];
    float b0 = in[n10], c0 = in[n20];
    float a1 = in[has1 ? i1 : 0];
    float b1 = in[n11], c1 = in[n21];
    out[i0] = (i0 == 0) ? 0.f : a0 + 0.5f * (b0 + c0);
    if (has1) out[i1] = a1 + 0.5f * (b1 + c1);
}

__global__ void k_blur4h_both2(const h4* __restrict__ inB, h4* __restrict__ outB,
                               const int* __restrict__ bnB, int Mb,
                               const h4* __restrict__ inS, h4* __restrict__ outS,
                               const int* __restrict__ bnS, int Ms) {
    int i = blockIdx.x * BLK + threadIdx.x;
    int PB = (Mb >> 1) + 1;
    int PS = (Ms >> 1) + 1;
    if (i < PB) blur4h_two(inB, outB, bnB, Mb, i);
    else if (i - PB < PS) blur4h_two(inS, outS, bnS, Ms, i - PB);
}

__global__ void k_blur4h_2(const h4* __restrict__ in, h4* __restrict__ out,
                           const int* __restrict__ bn, int M) {
    int p = blockIdx.x * BLK + threadIdx.x;
    if (p <= (M >> 1)) blur4h_two(in, out, bn, M, p);
}

__global__ void k_blur1_both2(const float* __restrict__ inB, float* __restrict__ outB,
                              const int* __restrict__ bnB, int Mb,
                              const float* __restrict__ inS, float* __restrict__ outS,
                              const int* __restrict__ bnS, int Ms) {
    int i = blockIdx.x * BLK + threadIdx.x;
    int PB = (Mb >> 1) + 1;
    int PS = (Ms >> 1) + 1;
    if (i < PB) blur1_two(inB, outB, bnB, Mb, i);
    else if (i - PB < PS) blur1_two(inS, outS, bnS, Ms, i - PB);
}

__global__ void k_blur1_2(const float* __restrict__ in, float* __restrict__ out,
                          const int* __restrict__ bn, int M) {
    int p = blockIdx.x * BLK + threadIdx.x;
    if (p <= (M >> 1)) blur1_two(in, out, bn, M, p);
}

// ---------------- normalizer slice + weight prescale ----------------
__global__ void k_norm_prescale(const float* __restrict__ nTb, const float* __restrict__ wsb,
                                const int* __restrict__ osb,
                                const float* __restrict__ nTs, const float* __restrict__ wss,
                                const int* __restrict__ oss,
                                float* __restrict__ wsbp, float* __restrict__ wssp) {
    int n = blockIdx.x * BLK + threadIdx.x;
    if (n >= NPIX) return;
    float sb = 0.f;
#pragma unroll
    for (int r = 0; r < 6; r++) sb += wsb[n * 6 + r] * nTb[osb[n * 6 + r]];
    float cb = BI_COMPAT * ALPHA_B / (ALPHA_B * sb + 1e-20f);
#pragma unroll
    for (int r = 0; r < 6; r++) wsbp[n * 6 + r] = wsb[n * 6 + r] * cb;
    float ss = 0.f;
#pragma unroll
    for (int r = 0; r < 3; r++) ss += wss[n * 3 + r] * nTs[oss[n * 3 + r]];
    float cs = SP_COMPAT * ALPHA_S / (ALPHA_S * ss + 1e-20f);
#pragma unroll
    for (int r = 0; r < 3; r++) wssp[n * 3 + r] = wss[n * 3 + r] * cs;
}

// ---------------- fused slice + message + softmax ----------------
__global__ void k_slice_combine_h(const float4* __restrict__ u,
                                  const h4* __restrict__ tb, const float* __restrict__ wsbp,
                                  const int* __restrict__ osb,
                                  const h4* __restrict__ ts, const float* __restrict__ wssp,
                                  const int* __restrict__ oss,
                                  float4* __restrict__ Qout) {
    int n = blockIdx.x * BLK + threadIdx.x;
    if (n >= NPIX) return;
    float4 uu = u[n];
    float l0 = -uu.x, l1 = -uu.y, l2 = -uu.z, l3 = -uu.w;
#pragma unroll
    for (int r = 0; r < 6; r++) {
        float w = wsbp[n * 6 + r];
        h4 t = tb[osb[n * 6 + r]];
        l0 += w * (float)t.x; l1 += w * (float)t.y; l2 += w * (float)t.z; l3 += w * (float)t.w;
    }
#pragma unroll
    for (int r = 0; r < 3; r++) {
        float w = wssp[n * 3 + r];
        h4 t = ts[oss[n * 3 + r]];
        l0 += w * (float)t.x; l1 += w * (float)t.y; l2 += w * (float)t.z; l3 += w * (float)t.w;
    }
    float m = fmaxf(fmaxf(l0, l1), fmaxf(l2, l3));
    float e0 = expf(l0 - m), e1 = expf(l1 - m), e2 = expf(l2 - m), e3 = expf(l3 - m);
    float inv = 1.0f / (e0 + e1 + e2 + e3);
    Qout[n] = make_float4(e0 * inv, e1 * inv, e2 * inv, e3 * inv);
}

// ---------------- fallback (fp32 atomic splat path) ----------------
__global__ void k_blur1(const float* __restrict__ in, float* __restrict__ out,
                        const int* __restrict__ bn, int M) {
    int i = blockIdx.x * BLK + threadIdx.x;
    if (i > M) return;
    if (i == 0) { out[0] = 0.f; return; }
    int n1 = bn[(size_t)(i - 1) * 2 + 0];
    int n2 = bn[(size_t)(i - 1) * 2 + 1];
    out[i] = in[i] + 0.5f * (in[n1] + in[n2]);
}

template <int D1>
__global__ void k_splat1(const float* __restrict__ ws, const int* __restrict__ os,
                         float* __restrict__ table) {
    int n = blockIdx.x * BLK + threadIdx.x;
    if (n >= NPIX) return;
#pragma unroll
    for (int r = 0; r < D1; r++) atomicAdd(&table[os[n * D1 + r]], ws[n * D1 + r]);
}

template <int D1>
__global__ void k_splat4(const float4* __restrict__ Q, const float* __restrict__ ws,
                         const int* __restrict__ os, float* __restrict__ table) {
    int n = blockIdx.x * BLK + threadIdx.x;
    if (n >= NPIX) return;
    float4 q = Q[n];
#pragma unroll
    for (int r = 0; r < D1; r++) {
        float w = ws[n * D1 + r];
        int o = os[n * D1 + r];
        float* t = table + 4 * (size_t)o;
        atomicAdd(t + 0, q.x * w);
        atomicAdd(t + 1, q.y * w);
        atomicAdd(t + 2, q.z * w);
        atomicAdd(t + 3, q.w * w);
    }
}

__global__ void k_blur4(const float4* __restrict__ in, float4* __restrict__ out,
                        const int* __restrict__ bn, int M) {
    int i = blockIdx.x * BLK + threadIdx.x;
    if (i > M) return;
    if (i == 0) { out[0] = f4zero(); return; }
    int n1 = bn[(size_t)(i - 1) * 2 + 0];
    int n2 = bn[(size_t)(i - 1) * 2 + 1];
    float4 a = in[i], b = in[n1], c = in[n2];
    out[i] = make_float4(a.x + 0.5f * (b.x + c.x), a.y + 0.5f * (b.y + c.y),
                         a.z + 0.5f * (b.z + c.z), a.w + 0.5f * (b.w + c.w));
}

template <int D1>
__global__ void k_norm_slice(const float* __restrict__ table, const float* __restrict__ ws,
                             const int* __restrict__ os, float alpha,
                             float* __restrict__ inv_out) {
    int n = blockIdx.x * BLK + threadIdx.x;
    if (n >= NPIX) return;
    float s = 0.f;
#pragma unroll
    for (int r = 0; r < D1; r++) s += ws[n * D1 + r] * table[os[n * D1 + r]];
    inv_out[n] = 1.0f / (alpha * s + 1e-20f);
}

__global__ void k_slice_combine(const float4* __restrict__ u,
                                const float4* __restrict__ tb, const float* __restrict__ wsb,
                                const int* __restrict__ osb,
                                const float4* __restrict__ ts, const float* __restrict__ wss,
                                const int* __restrict__ oss,
                                const float* __restrict__ inv_nb,
                                const float* __restrict__ inv_ns,
                                float4* __restrict__ Qout) {
    int n = blockIdx.x * BLK + threadIdx.x;
    if (n >= NPIX) return;
    float4 ab = f4zero();
#pragma unroll
    for (int r = 0; r < 6; r++) {
        float w = wsb[n * 6 + r];
        float4 t = tb[osb[n * 6 + r]];
        ab.x += w * t.x; ab.y += w * t.y; ab.z += w * t.z; ab.w += w * t.w;
    }
    float4 as = f4zero();
#pragma unroll
    for (int r = 0; r < 3; r++) {
        float w = wss[n * 3 + r];
        float4 t = ts[oss[n * 3 + r]];
        as.x += w * t.x; as.y += w * t.y; as.z += w * t.z; as.w += w * t.w;
    }
    float cb = BI_COMPAT * ALPHA_B * inv_nb[n];
    float cs = SP_COMPAT * ALPHA_S * inv_ns[n];
    float4 uu = u[n];
    float l0 = -uu.x + cb * ab.x + cs * as.x;
    float l1 = -uu.y + cb * ab.y + cs * as.y;
    float l2 = -uu.z + cb * ab.z + cs * as.z;
    float l3 = -uu.w + cb * ab.w + cs * as.w;
    float m = fmaxf(fmaxf(l0, l1), fmaxf(l2, l3));
    float e0 = expf(l0 - m), e1 = expf(l1 - m), e2 = expf(l2 - m), e3 = expf(l3 - m);
    float inv = 1.0f / (e0 + e1 + e2 + e3);
    Qout[n] = make_float4(e0 * inv, e1 * inv, e2 * inv, e3 * inv);
}

extern "C" void kernel_launch(void* const* d_in, const int* in_sizes, int n_in,
                              void* d_out, int out_size, void* d_ws, size_t ws_size,
                              hipStream_t stream) {
    const float* unary = (const float*)d_in[0];
    const float* wsb   = (const float*)d_in[1];
    const int*   osb   = (const int*)d_in[2];
    const int*   bnb   = (const int*)d_in[3];
    const float* wss   = (const float*)d_in[5];
    const int*   oss   = (const int*)d_in[6];
    const int*   bns   = (const int*)d_in[7];
    const int Mb = in_sizes[3] / 12;   // bn_b is (6, Mb, 2)
    const int Ms = in_sizes[7] / 6;    // bn_s is (3, Ms, 2)
    const int Vb = Mb + 1, Vs = Ms + 1;
    const int V = Vb + Vs;

    float* Q = (float*)d_out;  // N x 4, final value IS the output

    char* p = (char*)d_ws;
    auto alloc = [&](size_t nbytes) -> void* {
        void* r = (void*)p;
        p += (nbytes + 15) & ~(size_t)15;
        return r;
    };
    h4*   tAb  = (h4*)alloc((size_t)Vb * 8);
    h4*   tBb  = (h4*)alloc((size_t)Vb * 8);
    h4*   tAs  = (h4*)alloc((size_t)Vs * 8);
    h4*   tBs  = (h4*)alloc((size_t)Vs * 8);
    float* nAb = (float*)alloc((size_t)Vb * 4);
    float* nBb = (float*)alloc((size_t)Vb * 4);
    float* nAs = (float*)alloc((size_t)Vs * 4);
    float* nBs = (float*)alloc((size_t)Vs * 4);
    // wsbp (6N floats) and wssp (3N floats) are contiguous (6N*4 is 16B-aligned);
    // the 9N-int `next` array aliases them: next is dead after k_compact, and
    // wsbp/wssp are first written by k_norm_prescale (after k_compact completes).
    float* wsbp = (float*)alloc((size_t)NPIX * 6 * 4);
    float* wssp = (float*)alloc((size_t)NPIX * 3 * 4);
    int*   next = (int*)wsbp;
    int*  start = (int*)alloc((size_t)V * 4);
    int*  endv  = (int*)alloc((size_t)V * 4);
    int*  head  = (int*)alloc((size_t)V * 4);
    unsigned* ent = (unsigned*)alloc((size_t)TOTE * 4);
    int*  cursor = (int*)alloc(16);
    size_t need = (size_t)(p - (char*)d_ws);
    bool use_gather = need <= ws_size;

    dim3 blk(BLK);
    dim3 gN((NPIX + BLK - 1) / BLK);
    dim3 gV((V + BLK - 1) / BLK);
    // pair-kernel grids (2 vertices/thread)
    const int PB = Mb / 2 + 1, PS = Ms / 2 + 1;
    dim3 gP2((PB + PS + BLK - 1) / BLK);
    dim3 gPb((PB + BLK - 1) / BLK);

    if (use_gather) {
        // ---- build CSR via linked-list inversion + self-allocating compaction ----
        hipMemsetAsync(head, 0xFF, (size_t)V * 4, stream);  // -1 sentinel
        hipMemsetAsync(cursor, 0, 16, stream);
        k_link_softmax<<<gN, blk, 0, stream>>>(osb, oss, head, next,
                                               (const float4*)unary, (float4*)Q, Vb);
        k_compact<<<gV, blk, 0, stream>>>(head, next, wsb, wss, ent, start, endv,
                                          nAb, nAs, cursor, V, Vb);

        // ---- normalizer blur chain (C=1, fp32), then prescale slice weights ----
        {
            float* a = nAb; float* b = nBb;
            float* as_ = nAs; float* bs_ = nBs;
            for (int j = 0; j < 3; j++) {
                k_blur1_both2<<<gP2, blk, 0, stream>>>(a, b, bnb + (size_t)j * Mb * 2, Mb,
                                                       as_, bs_, bns + (size_t)j * Ms * 2, Ms);
                float* t = a; a = b; b = t;
                t = as_; as_ = bs_; bs_ = t;
            }
            for (int j = 3; j < 6; j++) {
                k_blur1_2<<<gPb, blk, 0, stream>>>(a, b, bnb + (size_t)j * Mb * 2, Mb);
                float* t = a; a = b; b = t;
            }
            // bilateral final in a, spatial final in as_
            k_norm_prescale<<<gN, blk, 0, stream>>>(a, wsb, osb, as_, wss, oss, wsbp, wssp);
        }

        // ---- 10 mean-field iterations ----
        for (int it = 0; it < 10; it++) {
            k_gather4h_both<<<gV, blk, 0, stream>>>(ent, start, endv, V, Vb, tAb, tAs,
                                                    (const float4*)Q);
            h4* a = tAb; h4* b = tBb;
            h4* as_ = tAs; h4* bs_ = tBs;
            for (int j = 0; j < 3; j++) {
                k_blur4h_both2<<<gP2, blk, 0, stream>>>(a, b, bnb + (size_t)j * Mb * 2, Mb,
                                                        as_, bs_, bns + (size_t)j * Ms * 2, Ms);
                h4* t = a; a = b; b = t;
                t = as_; as_ = bs_; bs_ = t;
            }
            for (int j = 3; j < 6; j++) {
                k_blur4h_2<<<gPb, blk, 0, stream>>>(a, b, bnb + (size_t)j * Mb * 2, Mb);
                h4* t = a; a = b; b = t;
            }
            // bilateral final in a (= tAb), spatial final in as_ (= tBs)
            k_slice_combine_h<<<gN, blk, 0, stream>>>((const float4*)unary,
                                                      a, wsbp, osb, as_, wssp, oss,
                                                      (float4*)Q);
        }
    } else {
        // ---- fallback: fp32 atomic splat path ----
        char* q = (char*)d_ws;
        auto alloc2 = [&](size_t nbytes) -> void* {
            void* r = (void*)q;
            q += (nbytes + 15) & ~(size_t)15;
            return r;
        };
        float* fAb = (float*)alloc2((size_t)Vb * 4 * sizeof(float));
        float* fBb = (float*)alloc2((size_t)Vb * 4 * sizeof(float));
        float* fAs = (float*)alloc2((size_t)Vs * 4 * sizeof(float));
        float* fBs = (float*)alloc2((size_t)Vs * 4 * sizeof(float));
        float* inv_nb = (float*)alloc2(NPIX * sizeof(float));
        float* inv_ns = (float*)alloc2(NPIX * sizeof(float));
        dim3 gMb((Mb + 1 + BLK - 1) / BLK);
        dim3 gMs((Ms + 1 + BLK - 1) / BLK);

        hipMemsetAsync(fAb, 0, (size_t)Vb * sizeof(float), stream);
        k_splat1<6><<<gN, blk, 0, stream>>>(wsb, osb, fAb);
        {
            float* a = fAb; float* b = fBb;
            for (int j = 0; j < 6; j++) {
                k_blur1<<<gMb, blk, 0, stream>>>(a, b, bnb + (size_t)j * Mb * 2, Mb);
                float* t = a; a = b; b = t;
            }
            k_norm_slice<6><<<gN, blk, 0, stream>>>(a, wsb, osb, ALPHA_B, inv_nb);
        }
        hipMemsetAsync(fAs, 0, (size_t)Vs * sizeof(float), stream);
        k_splat1<3><<<gN, blk, 0, stream>>>(wss, oss, fAs);
        {
            float* a = fAs; float* b = fBs;
            for (int j = 0; j < 3; j++) {
                k_blur1<<<gMs, blk, 0, stream>>>(a, b, bns + (size_t)j * Ms * 2, Ms);
                float* t = a; a = b; b = t;
            }
            k_norm_slice<3><<<gN, blk, 0, stream>>>(a, wss, oss, ALPHA_S, inv_ns);
        }
        k_softmax_init<<<gN, blk, 0, stream>>>((const float4*)unary, (float4*)Q);
        for (int it = 0; it < 10; it++) {
            hipMemsetAsync(fAb, 0, (size_t)Vb * 4 * sizeof(float), stream);
            k_splat4<6><<<gN, blk, 0, stream>>>((const float4*)Q, wsb, osb, fAb);
            float* a = fAb; float* b = fBb;
            for (int j = 0; j < 6; j++) {
                k_blur4<<<gMb, blk, 0, stream>>>((const float4*)a, (float4*)b,
                                                 bnb + (size_t)j * Mb * 2, Mb);
                float* t = a; a = b; b = t;
            }
            float* finb = a;
            hipMemsetAsync(fAs, 0, (size_t)Vs * 4 * sizeof(float), stream);
            k_splat4<3><<<gN, blk, 0, stream>>>((const float4*)Q, wss, oss, fAs);
            float* as_ = fAs; float* bs_ = fBs;
            for (int j = 0; j < 3; j++) {
                k_blur4<<<gMs, blk, 0, stream>>>((const float4*)as_, (float4*)bs_,
                                                 bns + (size_t)j * Ms * 2, Ms);
                float* t = as_; as_ = bs_; bs_ = t;
            }
            float* fins = as_;
            k_slice_combine<<<gN, blk, 0, stream>>>((const float4*)unary,
                                                    (const float4*)finb, wsb, osb,
                                                    (const float4*)fins, wss, oss,
                                                    inv_nb, inv_ns, (float4*)Q);
        }
    }
}

// Round 5
// 940.476 us; speedup vs baseline: 6.9902x; 1.0268x over previous
//
#include <hip/hip_runtime.h>

#define NPIX (512 * 512)
#define BLK 256

#define TOTB (NPIX * 6)
#define TOTS (NPIX * 3)
#define TOTE (NPIX * 9)

typedef _Float16 h4 __attribute__((ext_vector_type(4)));
typedef unsigned long long u64;

constexpr float ALPHA_B = 32.0f / 33.0f;   // 1/(1+2^-5)
constexpr float ALPHA_S = 0.8f;            // 1/(1+2^-2)
constexpr float BI_COMPAT = 10.0f;
constexpr float SP_COMPAT = 3.0f;

// 4-byte CSR entry: [31:18] = weight (14-bit fixed point, /16383), [17:0] = pixel id
__device__ __forceinline__ unsigned pack_ent(int n, float w) {
    float wc = fminf(fmaxf(w, 0.f), 1.f);
    unsigned iw = (unsigned)(wc * 16383.f + 0.5f);
    return (iw << 18) | (unsigned)n;
}
__device__ __forceinline__ int ent_pix(unsigned e) { return (int)(e & 0x3FFFFu); }
__device__ __forceinline__ float ent_w(unsigned e) {
    return (float)(e >> 18) * (1.0f / 16383.0f);
}
// 8-byte list node: high 32 = next entry id (int, -1 sentinel), low 32 = packed ent
__device__ __forceinline__ u64 mknode(int nxt, unsigned pay) {
    return ((u64)(unsigned)nxt << 32) | (u64)pay;
}

__device__ __forceinline__ float4 f4zero() { return make_float4(0.f, 0.f, 0.f, 0.f); }
__device__ __forceinline__ h4 h4zero() {
    h4 z; z.x = (_Float16)0.f; z.y = (_Float16)0.f; z.z = (_Float16)0.f; z.w = (_Float16)0.f;
    return z;
}

// ---------------- softmax init (fallback path) ----------------
__global__ void k_softmax_init(const float4* __restrict__ u, float4* __restrict__ Q) {
    int n = blockIdx.x * BLK + threadIdx.x;
    if (n >= NPIX) return;
    float4 uu = u[n];
    float l0 = -uu.x, l1 = -uu.y, l2 = -uu.z, l3 = -uu.w;
    float m = fmaxf(fmaxf(l0, l1), fmaxf(l2, l3));
    float e0 = expf(l0 - m), e1 = expf(l1 - m), e2 = expf(l2 - m), e3 = expf(l3 - m);
    float inv = 1.0f / (e0 + e1 + e2 + e3);
    Q[n] = make_float4(e0 * inv, e1 * inv, e2 * inv, e3 * inv);
}

// ---------------- wave-aggregated linked-list insertion (8B payload nodes) ----------------
// Lanes hold consecutive pixels. Runs of equal vertex o within a wave chain
// lane-to-lane locally; only the run head does the device atomicExch (one atomic
// per RUN, not per entry). Spatial vertices run ~3 long; bilateral are random
// (runs of 1 — degenerates to old behavior at zero extra cost, VALU is idle).
template <int D1>
__device__ __forceinline__ void link_slot(const int* __restrict__ os, const float* __restrict__ ws,
                                          int* __restrict__ head, u64* __restrict__ next2,
                                          int n, int r, int obase, int ebase, int lane) {
    int o = obase + os[n * D1 + r];
    int e = ebase + n * D1 + r;
    unsigned pay = pack_ent(n, ws[n * D1 + r]);
    int o_prev = __shfl_up(o, 1);
    bool is_head = (lane == 0) || (o != o_prev);
    u64 hm = __ballot(is_head);
    u64 above = (hm >> lane) >> 1;                       // head bits of lanes > lane
    int runlen = above ? __ffsll((long long)above) : (64 - lane);
    int e_prevlane = __shfl_up(e, 1);
    u64 node;
    if (is_head) {
        int e_last = e + (runlen - 1) * D1;              // consecutive pixels -> e steps by D1
        int old = atomicExch(&head[o], e_last);
        node = mknode(old, pay);
    } else {
        node = mknode(e_prevlane, pay);
    }
    next2[e] = node;
}

// NOTE: NPIX % BLK == 0 and BLK % 64 == 0 -> all waves fully active (ballot-safe).
__global__ void k_link2_softmax(const int* __restrict__ osb, const float* __restrict__ wsb,
                                const int* __restrict__ oss, const float* __restrict__ wss,
                                int* __restrict__ head, u64* __restrict__ next2,
                                const float4* __restrict__ u, float4* __restrict__ Q,
                                int Vb) {
    int n = blockIdx.x * BLK + threadIdx.x;
    float4 uu = u[n];
    float l0 = -uu.x, l1 = -uu.y, l2 = -uu.z, l3 = -uu.w;
    float m = fmaxf(fmaxf(l0, l1), fmaxf(l2, l3));
    float e0 = expf(l0 - m), e1 = expf(l1 - m), e2 = expf(l2 - m), e3 = expf(l3 - m);
    float inv = 1.0f / (e0 + e1 + e2 + e3);
    Q[n] = make_float4(e0 * inv, e1 * inv, e2 * inv, e3 * inv);
    int lane = threadIdx.x & 63;
#pragma unroll
    for (int r = 0; r < 6; r++) link_slot<6>(osb, wsb, head, next2, n, r, 0, 0, lane);
#pragma unroll
    for (int r = 0; r < 3; r++) link_slot<3>(oss, wss, head, next2, n, r, Vb, TOTB, lane);
}

// ---------------- CSR compaction, 8B nodes (no weight re-read, no division) ----------------
__global__ void k_compact2(const int* __restrict__ head, const u64* __restrict__ next2,
                           unsigned* __restrict__ ent, int* __restrict__ start,
                           int* __restrict__ endv,
                           float* __restrict__ nB, float* __restrict__ nS,
                           int* __restrict__ cursor, int V, int Vb) {
    __shared__ int lds[BLK];
    __shared__ int sbase;
    int o = blockIdx.x * BLK + threadIdx.x;
    bool valid = o < V;
    int h = valid ? head[o] : -1;
    int len = 0;
    for (int e = h; e >= 0;) { e = (int)(next2[e] >> 32); len++; }
    lds[threadIdx.x] = len;
    __syncthreads();
    for (int off = 1; off < BLK; off <<= 1) {
        int t = ((int)threadIdx.x >= off) ? lds[threadIdx.x - off] : 0;
        __syncthreads();
        lds[threadIdx.x] += t;
        __syncthreads();
    }
    int incl = lds[threadIdx.x];
    if (threadIdx.x == BLK - 1) sbase = atomicAdd(cursor, incl);
    __syncthreads();
    if (!valid) return;
    int pos = sbase + incl - len;
    start[o] = pos;
    endv[o] = pos + len;
    float acc = 0.f;
    for (int e = h; e >= 0;) {
        u64 nd = next2[e];
        unsigned pe = (unsigned)nd;
        acc += ent_w(pe);
        ent[pos++] = pe;
        e = (int)(nd >> 32);
    }
    if (o < Vb) nB[o] = acc;
    else nS[o - Vb] = acc;
}

// ---------------- legacy 4B-node build (fallback when next2 doesn't fit alias) ----------------
__global__ void k_link_softmax(const int* __restrict__ osb, const int* __restrict__ oss,
                               int* __restrict__ head, int* __restrict__ next,
                               const float4* __restrict__ u, float4* __restrict__ Q,
                               int Vb) {
    int n = blockIdx.x * BLK + threadIdx.x;
    if (n >= NPIX) return;
    float4 uu = u[n];
    float l0 = -uu.x, l1 = -uu.y, l2 = -uu.z, l3 = -uu.w;
    float m = fmaxf(fmaxf(l0, l1), fmaxf(l2, l3));
    float e0 = expf(l0 - m), e1 = expf(l1 - m), e2 = expf(l2 - m), e3 = expf(l3 - m);
    float inv = 1.0f / (e0 + e1 + e2 + e3);
    Q[n] = make_float4(e0 * inv, e1 * inv, e2 * inv, e3 * inv);
#pragma unroll
    for (int r = 0; r < 6; r++) {
        int o = osb[n * 6 + r];
        int e = n * 6 + r;
        next[e] = atomicExch(&head[o], e);
    }
#pragma unroll
    for (int r = 0; r < 3; r++) {
        int o = Vb + oss[n * 3 + r];
        int e = TOTB + n * 3 + r;
        next[e] = atomicExch(&head[o], e);
    }
}

__global__ void k_compact(const int* __restrict__ head, const int* __restrict__ next,
                          const float* __restrict__ wsb, const float* __restrict__ wss,
                          unsigned* __restrict__ ent, int* __restrict__ start,
                          int* __restrict__ endv,
                          float* __restrict__ nB, float* __restrict__ nS,
                          int* __restrict__ cursor, int V, int Vb) {
    __shared__ int lds[BLK];
    __shared__ int sbase;
    int o = blockIdx.x * BLK + threadIdx.x;
    bool valid = o < V;
    int h = valid ? head[o] : -1;
    int len = 0;
    for (int e = h; e >= 0; e = next[e]) len++;
    lds[threadIdx.x] = len;
    __syncthreads();
    for (int off = 1; off < BLK; off <<= 1) {
        int t = ((int)threadIdx.x >= off) ? lds[threadIdx.x - off] : 0;
        __syncthreads();
        lds[threadIdx.x] += t;
        __syncthreads();
    }
    int incl = lds[threadIdx.x];
    if (threadIdx.x == BLK - 1) sbase = atomicAdd(cursor, incl);
    __syncthreads();
    if (!valid) return;
    int pos = sbase + incl - len;
    start[o] = pos;
    endv[o] = pos + len;
    float acc = 0.f;
    if (o < Vb) {
        for (int e = h; e >= 0; e = next[e]) {
            unsigned n = (unsigned)e / 6u;
            unsigned pe = pack_ent((int)n, wsb[e]);
            acc += ent_w(pe);
            ent[pos++] = pe;
        }
        nB[o] = acc;
    } else {
        for (int e = h; e >= 0; e = next[e]) {
            int ee = e - TOTB;
            unsigned pe = pack_ent(ee / 3, wss[ee]);
            acc += ent_w(pe);
            ent[pos++] = pe;
        }
        nS[o - Vb] = acc;
    }
}

// ---------------- gather-based splat (single concatenated CSR) ----------------
__global__ void k_gather4h_both(const unsigned* __restrict__ ent, const int* __restrict__ start,
                                const int* __restrict__ endv, int V, int Vb,
                                h4* __restrict__ tB, h4* __restrict__ tS,
                                const float4* __restrict__ Q) {
    int i = blockIdx.x * BLK + threadIdx.x;
    if (i >= V) return;
    int s = start[i];
    int e = endv[i];
    float ax = 0.f, ay = 0.f, az = 0.f, aw = 0.f;
    for (int k = s; k < e; k++) {
        unsigned en = ent[k];
        float w = ent_w(en);
        float4 q = Q[ent_pix(en)];
        ax += w * q.x; ay += w * q.y; az += w * q.z; aw += w * q.w;
    }
    h4 h;
    h.x = (_Float16)ax; h.y = (_Float16)ay; h.z = (_Float16)az; h.w = (_Float16)aw;
    if (i < Vb) tB[i] = h;
    else tS[i - Vb] = h;
}

// ---------------- blur (R2-proven 1-vertex/thread versions) ----------------
__global__ void k_blur1(const float* __restrict__ in, float* __restrict__ out,
                        const int* __restrict__ bn, int M) {
    int i = blockIdx.x * BLK + threadIdx.x;
    if (i > M) return;
    if (i == 0) { out[0] = 0.f; return; }
    int n1 = bn[(size_t)(i - 1) * 2 + 0];
    int n2 = bn[(size_t)(i - 1) * 2 + 1];
    out[i] = in[i] + 0.5f * (in[n1] + in[n2]);
}

__global__ void k_blur1_both(const float* __restrict__ inB, float* __restrict__ outB,
                             const int* __restrict__ bnB, int Mb,
                             const float* __restrict__ inS, float* __restrict__ outS,
                             const int* __restrict__ bnS, int Ms) {
    int i = blockIdx.x * BLK + threadIdx.x;
    const float* in; float* out; const int* bn; int M, idx;
    if (i <= Mb) { in = inB; out = outB; bn = bnB; M = Mb; idx = i; }
    else {
        idx = i - (Mb + 1);
        if (idx > Ms) return;
        in = inS; out = outS; bn = bnS; M = Ms;
    }
    if (idx == 0) { out[0] = 0.f; return; }
    int n1 = bn[(size_t)(idx - 1) * 2 + 0];
    int n2 = bn[(size_t)(idx - 1) * 2 + 1];
    out[idx] = in[idx] + 0.5f * (in[n1] + in[n2]);
}

__global__ void k_blur4h(const h4* __restrict__ in, h4* __restrict__ out,
                         const int* __restrict__ bn, int M) {
    int i = blockIdx.x * BLK + threadIdx.x;
    if (i > M) return;
    if (i == 0) { out[0] = h4zero(); return; }
    int n1 = bn[(size_t)(i - 1) * 2 + 0];
    int n2 = bn[(size_t)(i - 1) * 2 + 1];
    h4 a = in[i], b = in[n1], c = in[n2];
    h4 o;
    o.x = (_Float16)((float)a.x + 0.5f * ((float)b.x + (float)c.x));
    o.y = (_Float16)((float)a.y + 0.5f * ((float)b.y + (float)c.y));
    o.z = (_Float16)((float)a.z + 0.5f * ((float)b.z + (float)c.z));
    o.w = (_Float16)((float)a.w + 0.5f * ((float)b.w + (float)c.w));
    out[i] = o;
}

__global__ void k_blur4h_both(const h4* __restrict__ inB, h4* __restrict__ outB,
                              const int* __restrict__ bnB, int Mb,
                              const h4* __restrict__ inS, h4* __restrict__ outS,
                              const int* __restrict__ bnS, int Ms) {
    int i = blockIdx.x * BLK + threadIdx.x;
    const h4* in; h4* out; const int* bn; int M, idx;
    if (i <= Mb) { in = inB; out = outB; bn = bnB; M = Mb; idx = i; }
    else {
        idx = i - (Mb + 1);
        if (idx > Ms) return;
        in = inS; out = outS; bn = bnS; M = Ms;
    }
    if (idx == 0) { out[0] = h4zero(); return; }
    int n1 = bn[(size_t)(idx - 1) * 2 + 0];
    int n2 = bn[(size_t)(idx - 1) * 2 + 1];
    h4 a = in[idx], b = in[n1], c = in[n2];
    h4 o;
    o.x = (_Float16)((float)a.x + 0.5f * ((float)b.x + (float)c.x));
    o.y = (_Float16)((float)a.y + 0.5f * ((float)b.y + (float)c.y));
    o.z = (_Float16)((float)a.z + 0.5f * ((float)b.z + (float)c.z));
    o.w = (_Float16)((float)a.w + 0.5f * ((float)b.w + (float)c.w));
    out[idx] = o;
}

// ---------------- normalizer slice + weight prescale ----------------
__global__ void k_norm_prescale(const float* __restrict__ nTb, const float* __restrict__ wsb,
                                const int* __restrict__ osb,
                                const float* __restrict__ nTs, const float* __restrict__ wss,
                                const int* __restrict__ oss,
                                float* __restrict__ wsbp, float* __restrict__ wssp) {
    int n = blockIdx.x * BLK + threadIdx.x;
    if (n >= NPIX) return;
    float sb = 0.f;
#pragma unroll
    for (int r = 0; r < 6; r++) sb += wsb[n * 6 + r] * nTb[osb[n * 6 + r]];
    float cb = BI_COMPAT * ALPHA_B / (ALPHA_B * sb + 1e-20f);
#pragma unroll
    for (int r = 0; r < 6; r++) wsbp[n * 6 + r] = wsb[n * 6 + r] * cb;
    float ss = 0.f;
#pragma unroll
    for (int r = 0; r < 3; r++) ss += wss[n * 3 + r] * nTs[oss[n * 3 + r]];
    float cs = SP_COMPAT * ALPHA_S / (ALPHA_S * ss + 1e-20f);
#pragma unroll
    for (int r = 0; r < 3; r++) wssp[n * 3 + r] = wss[n * 3 + r] * cs;
}

// ---------------- fused slice + message + softmax ----------------
__global__ void k_slice_combine_h(const float4* __restrict__ u,
                                  const h4* __restrict__ tb, const float* __restrict__ wsbp,
                                  const int* __restrict__ osb,
                                  const h4* __restrict__ ts, const float* __restrict__ wssp,
                                  const int* __restrict__ oss,
                                  float4* __restrict__ Qout) {
    int n = blockIdx.x * BLK + threadIdx.x;
    if (n >= NPIX) return;
    float4 uu = u[n];
    float l0 = -uu.x, l1 = -uu.y, l2 = -uu.z, l3 = -uu.w;
#pragma unroll
    for (int r = 0; r < 6; r++) {
        float w = wsbp[n * 6 + r];
        h4 t = tb[osb[n * 6 + r]];
        l0 += w * (float)t.x; l1 += w * (float)t.y; l2 += w * (float)t.z; l3 += w * (float)t.w;
    }
#pragma unroll
    for (int r = 0; r < 3; r++) {
        float w = wssp[n * 3 + r];
        h4 t = ts[oss[n * 3 + r]];
        l0 += w * (float)t.x; l1 += w * (float)t.y; l2 += w * (float)t.z; l3 += w * (float)t.w;
    }
    float m = fmaxf(fmaxf(l0, l1), fmaxf(l2, l3));
    float e0 = expf(l0 - m), e1 = expf(l1 - m), e2 = expf(l2 - m), e3 = expf(l3 - m);
    float inv = 1.0f / (e0 + e1 + e2 + e3);
    Qout[n] = make_float4(e0 * inv, e1 * inv, e2 * inv, e3 * inv);
}

// ---------------- fallback (fp32 atomic splat path) ----------------
template <int D1>
__global__ void k_splat1(const float* __restrict__ ws, const int* __restrict__ os,
                         float* __restrict__ table) {
    int n = blockIdx.x * BLK + threadIdx.x;
    if (n >= NPIX) return;
#pragma unroll
    for (int r = 0; r < D1; r++) atomicAdd(&table[os[n * D1 + r]], ws[n * D1 + r]);
}

template <int D1>
__global__ void k_splat4(const float4* __restrict__ Q, const float* __restrict__ ws,
                         const int* __restrict__ os, float* __restrict__ table) {
    int n = blockIdx.x * BLK + threadIdx.x;
    if (n >= NPIX) return;
    float4 q = Q[n];
#pragma unroll
    for (int r = 0; r < D1; r++) {
        float w = ws[n * D1 + r];
        int o = os[n * D1 + r];
        float* t = table + 4 * (size_t)o;
        atomicAdd(t + 0, q.x * w);
        atomicAdd(t + 1, q.y * w);
        atomicAdd(t + 2, q.z * w);
        atomicAdd(t + 3, q.w * w);
    }
}

__global__ void k_blur4(const float4* __restrict__ in, float4* __restrict__ out,
                        const int* __restrict__ bn, int M) {
    int i = blockIdx.x * BLK + threadIdx.x;
    if (i > M) return;
    if (i == 0) { out[0] = f4zero(); return; }
    int n1 = bn[(size_t)(i - 1) * 2 + 0];
    int n2 = bn[(size_t)(i - 1) * 2 + 1];
    float4 a = in[i], b = in[n1], c = in[n2];
    out[i] = make_float4(a.x + 0.5f * (b.x + c.x), a.y + 0.5f * (b.y + c.y),
                         a.z + 0.5f * (b.z + c.z), a.w + 0.5f * (b.w + c.w));
}

template <int D1>
__global__ void k_norm_slice(const float* __restrict__ table, const float* __restrict__ ws,
                             const int* __restrict__ os, float alpha,
                             float* __restrict__ inv_out) {
    int n = blockIdx.x * BLK + threadIdx.x;
    if (n >= NPIX) return;
    float s = 0.f;
#pragma unroll
    for (int r = 0; r < D1; r++) s += ws[n * D1 + r] * table[os[n * D1 + r]];
    inv_out[n] = 1.0f / (alpha * s + 1e-20f);
}

__global__ void k_slice_combine(const float4* __restrict__ u,
                                const float4* __restrict__ tb, const float* __restrict__ wsb,
                                const int* __restrict__ osb,
                                const float4* __restrict__ ts, const float* __restrict__ wss,
                                const int* __restrict__ oss,
                                const float* __restrict__ inv_nb,
                                const float* __restrict__ inv_ns,
                                float4* __restrict__ Qout) {
    int n = blockIdx.x * BLK + threadIdx.x;
    if (n >= NPIX) return;
    float4 ab = f4zero();
#pragma unroll
    for (int r = 0; r < 6; r++) {
        float w = wsb[n * 6 + r];
        float4 t = tb[osb[n * 6 + r]];
        ab.x += w * t.x; ab.y += w * t.y; ab.z += w * t.z; ab.w += w * t.w;
    }
    float4 as = f4zero();
#pragma unroll
    for (int r = 0; r < 3; r++) {
        float w = wss[n * 3 + r];
        float4 t = ts[oss[n * 3 + r]];
        as.x += w * t.x; as.y += w * t.y; as.z += w * t.z; as.w += w * t.w;
    }
    float cb = BI_COMPAT * ALPHA_B * inv_nb[n];
    float cs = SP_COMPAT * ALPHA_S * inv_ns[n];
    float4 uu = u[n];
    float l0 = -uu.x + cb * ab.x + cs * as.x;
    float l1 = -uu.y + cb * ab.y + cs * as.y;
    float l2 = -uu.z + cb * ab.z + cs * as.z;
    float l3 = -uu.w + cb * ab.w + cs * as.w;
    float m = fmaxf(fmaxf(l0, l1), fmaxf(l2, l3));
    float e0 = expf(l0 - m), e1 = expf(l1 - m), e2 = expf(l2 - m), e3 = expf(l3 - m);
    float inv = 1.0f / (e0 + e1 + e2 + e3);
    Qout[n] = make_float4(e0 * inv, e1 * inv, e2 * inv, e3 * inv);
}

extern "C" void kernel_launch(void* const* d_in, const int* in_sizes, int n_in,
                              void* d_out, int out_size, void* d_ws, size_t ws_size,
                              hipStream_t stream) {
    const float* unary = (const float*)d_in[0];
    const float* wsb   = (const float*)d_in[1];
    const int*   osb   = (const int*)d_in[2];
    const int*   bnb   = (const int*)d_in[3];
    const float* wss   = (const float*)d_in[5];
    const int*   oss   = (const int*)d_in[6];
    const int*   bns   = (const int*)d_in[7];
    const int Mb = in_sizes[3] / 12;   // bn_b is (6, Mb, 2)
    const int Ms = in_sizes[7] / 6;    // bn_s is (3, Ms, 2)
    const int Vb = Mb + 1, Vs = Ms + 1;
    const int V = Vb + Vs;

    float* Q = (float*)d_out;  // N x 4, final value IS the output

    char* p = (char*)d_ws;
    auto alloc = [&](size_t nbytes) -> void* {
        void* r = (void*)p;
        p += (nbytes + 15) & ~(size_t)15;
        return r;
    };
    // ---- aliasable region: everything here is first WRITTEN after k_compact* ----
    // wsbp/wssp: written by k_norm_prescale; tA*/tB*: written by iteration-1
    // gather/blur; nBb/nBs: written by first norm blur. The 8B next2 list
    // (18.9 MB) lives here during link+compact, then dies.
    char* region0 = p;
    float* wsbp = (float*)alloc((size_t)NPIX * 6 * 4);
    float* wssp = (float*)alloc((size_t)NPIX * 3 * 4);
    h4*   tAb  = (h4*)alloc((size_t)Vb * 8);
    h4*   tBb  = (h4*)alloc((size_t)Vb * 8);
    h4*   tAs  = (h4*)alloc((size_t)Vs * 8);
    h4*   tBs  = (h4*)alloc((size_t)Vs * 8);
    float* nBb = (float*)alloc((size_t)Vb * 4);
    float* nBs = (float*)alloc((size_t)Vs * 4);
    size_t region_bytes = (size_t)(p - region0);
    // ---- non-aliased (live across build) ----
    float* nAb = (float*)alloc((size_t)Vb * 4);   // written by k_compact*
    float* nAs = (float*)alloc((size_t)Vs * 4);
    int*  start = (int*)alloc((size_t)V * 4);
    int*  endv  = (int*)alloc((size_t)V * 4);
    int*  head  = (int*)alloc((size_t)V * 4);
    unsigned* ent = (unsigned*)alloc((size_t)TOTE * 4);
    int*  cursor = (int*)alloc(16);
    size_t need = (size_t)(p - (char*)d_ws);
    bool use_gather = need <= ws_size;
    bool use8 = region_bytes >= (size_t)TOTE * 8;   // does next2 fit the alias region?
    u64*  next2 = (u64*)region0;
    int*  next4 = (int*)region0;                    // legacy 4B nodes (always fit)

    dim3 blk(BLK);
    dim3 gN((NPIX + BLK - 1) / BLK);
    dim3 gVb((Vb + BLK - 1) / BLK);
    dim3 gV((V + BLK - 1) / BLK);
    dim3 gVBS((Vb + Vs + 1 + BLK - 1) / BLK);

    if (use_gather) {
        // ---- build CSR via (wave-aggregated) linked-list inversion + compaction ----
        hipMemsetAsync(head, 0xFF, (size_t)V * 4, stream);  // -1 sentinel
        hipMemsetAsync(cursor, 0, 16, stream);
        if (use8) {
            k_link2_softmax<<<gN, blk, 0, stream>>>(osb, wsb, oss, wss, head, next2,
                                                    (const float4*)unary, (float4*)Q, Vb);
            k_compact2<<<gV, blk, 0, stream>>>(head, next2, ent, start, endv,
                                               nAb, nAs, cursor, V, Vb);
        } else {
            k_link_softmax<<<gN, blk, 0, stream>>>(osb, oss, head, next4,
                                                   (const float4*)unary, (float4*)Q, Vb);
            k_compact<<<gV, blk, 0, stream>>>(head, next4, wsb, wss, ent, start, endv,
                                              nAb, nAs, cursor, V, Vb);
        }

        // ---- normalizer blur chain (C=1, fp32), then prescale slice weights ----
        {
            float* a = nAb; float* b = nBb;
            float* as_ = nAs; float* bs_ = nBs;
            for (int j = 0; j < 3; j++) {
                k_blur1_both<<<gVBS, blk, 0, stream>>>(a, b, bnb + (size_t)j * Mb * 2, Mb,
                                                       as_, bs_, bns + (size_t)j * Ms * 2, Ms);
                float* t = a; a = b; b = t;
                t = as_; as_ = bs_; bs_ = t;
            }
            for (int j = 3; j < 6; j++) {
                k_blur1<<<gVb, blk, 0, stream>>>(a, b, bnb + (size_t)j * Mb * 2, Mb);
                float* t = a; a = b; b = t;
            }
            // bilateral final in a (= nAb), spatial final in as_ (= nBs)
            k_norm_prescale<<<gN, blk, 0, stream>>>(a, wsb, osb, as_, wss, oss, wsbp, wssp);
        }

        // ---- 10 mean-field iterations ----
        for (int it = 0; it < 10; it++) {
            k_gather4h_both<<<gV, blk, 0, stream>>>(ent, start, endv, V, Vb, tAb, tAs,
                                                    (const float4*)Q);
            h4* a = tAb; h4* b = tBb;
            h4* as_ = tAs; h4* bs_ = tBs;
            for (int j = 0; j < 3; j++) {
                k_blur4h_both<<<gVBS, blk, 0, stream>>>(a, b, bnb + (size_t)j * Mb * 2, Mb,
                                                        as_, bs_, bns + (size_t)j * Ms * 2, Ms);
                h4* t = a; a = b; b = t;
                t = as_; as_ = bs_; bs_ = t;
            }
            for (int j = 3; j < 6; j++) {
                k_blur4h<<<gVb, blk, 0, stream>>>(a, b, bnb + (size_t)j * Mb * 2, Mb);
                h4* t = a; a = b; b = t;
            }
            // bilateral final in a (= tAb), spatial final in as_ (= tBs)
            k_slice_combine_h<<<gN, blk, 0, stream>>>((const float4*)unary,
                                                      a, wsbp, osb, as_, wssp, oss,
                                                      (float4*)Q);
        }
    } else {
        // ---- fallback: fp32 atomic splat path ----
        char* q = (char*)d_ws;
        auto alloc2 = [&](size_t nbytes) -> void* {
            void* r = (void*)q;
            q += (nbytes + 15) & ~(size_t)15;
            return r;
        };
        float* fAb = (float*)alloc2((size_t)Vb * 4 * sizeof(float));
        float* fBb = (float*)alloc2((size_t)Vb * 4 * sizeof(float));
        float* fAs = (float*)alloc2((size_t)Vs * 4 * sizeof(float));
        float* fBs = (float*)alloc2((size_t)Vs * 4 * sizeof(float));
        float* inv_nb = (float*)alloc2(NPIX * sizeof(float));
        float* inv_ns = (float*)alloc2(NPIX * sizeof(float));
        dim3 gMb((Mb + 1 + BLK - 1) / BLK);
        dim3 gMs((Ms + 1 + BLK - 1) / BLK);

        hipMemsetAsync(fAb, 0, (size_t)Vb * sizeof(float), stream);
        k_splat1<6><<<gN, blk, 0, stream>>>(wsb, osb, fAb);
        {
            float* a = fAb; float* b = fBb;
            for (int j = 0; j < 6; j++) {
                k_blur1<<<gMb, blk, 0, stream>>>(a, b, bnb + (size_t)j * Mb * 2, Mb);
                float* t = a; a = b; b = t;
            }
            k_norm_slice<6><<<gN, blk, 0, stream>>>(a, wsb, osb, ALPHA_B, inv_nb);
        }
        hipMemsetAsync(fAs, 0, (size_t)Vs * sizeof(float), stream);
        k_splat1<3><<<gN, blk, 0, stream>>>(wss, oss, fAs);
        {
            float* a = fAs; float* b = fBs;
            for (int j = 0; j < 3; j++) {
                k_blur1<<<gMs, blk, 0, stream>>>(a, b, bns + (size_t)j * Ms * 2, Ms);
                float* t = a; a = b; b = t;
            }
            k_norm_slice<3><<<gN, blk, 0, stream>>>(a, wss, oss, ALPHA_S, inv_ns);
        }
        k_softmax_init<<<gN, blk, 0, stream>>>((const float4*)unary, (float4*)Q);
        for (int it = 0; it < 10; it++) {
            hipMemsetAsync(fAb, 0, (size_t)Vb * 4 * sizeof(float), stream);
            k_splat4<6><<<gN, blk, 0, stream>>>((const float4*)Q, wsb, osb, fAb);
            float* a = fAb; float* b = fBb;
            for (int j = 0; j < 6; j++) {
                k_blur4<<<gMb, blk, 0, stream>>>((const float4*)a, (float4*)b,
                                                 bnb + (size_t)j * Mb * 2, Mb);
                float* t = a; a = b; b = t;
            }
            float* finb = a;
            hipMemsetAsync(fAs, 0, (size_t)Vs * 4 * sizeof(float), stream);
            k_splat4<3><<<gN, blk, 0, stream>>>((const float4*)Q, wss, oss, fAs);
            float* as_ = fAs; float* bs_ = fBs;
            for (int j = 0; j < 3; j++) {
                k_blur4<<<gMs, blk, 0, stream>>>((const float4*)as_, (float4*)bs_,
                                                 bns + (size_t)j * Ms * 2, Ms);
                float* t = as_; as_ = bs_; bs_ = t;
            }
            float* fins = as_;
            k_slice_combine<<<gN, blk, 0, stream>>>((const float4*)unary,
                                                    (const float4*)finb, wsb, osb,
                                                    (const float4*)fins, wss, oss,
                                                    inv_nb, inv_ns, (float4*)Q);
        }
    }
}

// Round 6
// 927.707 us; speedup vs baseline: 7.0864x; 1.0138x over previous
//
#include <hip/hip_runtime.h>

#define NPIX (512 * 512)
#define BLK 256

#define TOTB (NPIX * 6)
#define TOTS (NPIX * 3)
#define TOTE (NPIX * 9)

typedef _Float16 h4 __attribute__((ext_vector_type(4)));
typedef unsigned long long u64;

constexpr float ALPHA_B = 32.0f / 33.0f;   // 1/(1+2^-5)
constexpr float ALPHA_S = 0.8f;            // 1/(1+2^-2)
constexpr float BI_COMPAT = 10.0f;
constexpr float SP_COMPAT = 3.0f;

// 4-byte CSR entry: [31:18] = weight (14-bit fixed point, /16383), [17:0] = pixel id
__device__ __forceinline__ unsigned pack_ent(int n, float w) {
    float wc = fminf(fmaxf(w, 0.f), 1.f);
    unsigned iw = (unsigned)(wc * 16383.f + 0.5f);
    return (iw << 18) | (unsigned)n;
}
__device__ __forceinline__ int ent_pix(unsigned e) { return (int)(e & 0x3FFFFu); }
__device__ __forceinline__ float ent_w(unsigned e) {
    return (float)(e >> 18) * (1.0f / 16383.0f);
}
// 8-byte list node: high 32 = next entry id (int, -1 sentinel), low 32 = packed ent
__device__ __forceinline__ u64 mknode(int nxt, unsigned pay) {
    return ((u64)(unsigned)nxt << 32) | (u64)pay;
}

__device__ __forceinline__ float4 f4zero() { return make_float4(0.f, 0.f, 0.f, 0.f); }
__device__ __forceinline__ h4 h4zero() {
    h4 z; z.x = (_Float16)0.f; z.y = (_Float16)0.f; z.z = (_Float16)0.f; z.w = (_Float16)0.f;
    return z;
}

// ---------------- softmax init (fallback path) ----------------
__global__ void k_softmax_init(const float4* __restrict__ u, float4* __restrict__ Q) {
    int n = blockIdx.x * BLK + threadIdx.x;
    if (n >= NPIX) return;
    float4 uu = u[n];
    float l0 = -uu.x, l1 = -uu.y, l2 = -uu.z, l3 = -uu.w;
    float m = fmaxf(fmaxf(l0, l1), fmaxf(l2, l3));
    float e0 = expf(l0 - m), e1 = expf(l1 - m), e2 = expf(l2 - m), e3 = expf(l3 - m);
    float inv = 1.0f / (e0 + e1 + e2 + e3);
    Q[n] = make_float4(e0 * inv, e1 * inv, e2 * inv, e3 * inv);
}

// ---------------- wave-aggregated linked-list insertion (8B payload nodes) ----------------
// Lanes hold consecutive pixels. Runs of equal vertex o within a wave chain
// lane-to-lane locally; only the run head does the device atomicExch (one atomic
// per RUN, not per entry). Spatial vertices run ~3 long; bilateral are random
// (runs of 1 — degenerates to old behavior; the ballot math is free, VALU ~idle).
template <int D1>
__device__ __forceinline__ void link_slot(const int* __restrict__ os, const float* __restrict__ ws,
                                          int* __restrict__ head, u64* __restrict__ next2,
                                          int n, int r, int obase, int ebase, int lane) {
    int o = obase + os[n * D1 + r];
    int e = ebase + n * D1 + r;
    unsigned pay = pack_ent(n, ws[n * D1 + r]);
    int o_prev = __shfl_up(o, 1);
    bool is_head = (lane == 0) || (o != o_prev);
    u64 hm = __ballot(is_head);
    u64 above = (hm >> lane) >> 1;                       // head bits of lanes > lane
    int runlen = above ? __ffsll((long long)above) : (64 - lane);
    int e_prevlane = __shfl_up(e, 1);
    u64 node;
    if (is_head) {
        int e_last = e + (runlen - 1) * D1;              // consecutive pixels -> e steps by D1
        int old = atomicExch(&head[o], e_last);
        node = mknode(old, pay);
    } else {
        node = mknode(e_prevlane, pay);
    }
    next2[e] = node;
}

// NOTE: NPIX % BLK == 0 and BLK % 64 == 0 -> all waves fully active (ballot-safe).
__global__ void k_link2_softmax(const int* __restrict__ osb, const float* __restrict__ wsb,
                                const int* __restrict__ oss, const float* __restrict__ wss,
                                int* __restrict__ head, u64* __restrict__ next2,
                                const float4* __restrict__ u, float4* __restrict__ Q,
                                int Vb) {
    int n = blockIdx.x * BLK + threadIdx.x;
    float4 uu = u[n];
    float l0 = -uu.x, l1 = -uu.y, l2 = -uu.z, l3 = -uu.w;
    float m = fmaxf(fmaxf(l0, l1), fmaxf(l2, l3));
    float e0 = expf(l0 - m), e1 = expf(l1 - m), e2 = expf(l2 - m), e3 = expf(l3 - m);
    float inv = 1.0f / (e0 + e1 + e2 + e3);
    Q[n] = make_float4(e0 * inv, e1 * inv, e2 * inv, e3 * inv);
    int lane = threadIdx.x & 63;
#pragma unroll
    for (int r = 0; r < 6; r++) link_slot<6>(osb, wsb, head, next2, n, r, 0, 0, lane);
#pragma unroll
    for (int r = 0; r < 3; r++) link_slot<3>(oss, wss, head, next2, n, r, Vb, TOTB, lane);
}

// ---------------- CSR compaction, 8B nodes (no weight re-read, no division) ----------------
__global__ void k_compact2(const int* __restrict__ head, const u64* __restrict__ next2,
                           unsigned* __restrict__ ent, int* __restrict__ start,
                           int* __restrict__ endv,
                           float* __restrict__ nB, float* __restrict__ nS,
                           int* __restrict__ cursor, int V, int Vb) {
    __shared__ int lds[BLK];
    __shared__ int sbase;
    int o = blockIdx.x * BLK + threadIdx.x;
    bool valid = o < V;
    int h = valid ? head[o] : -1;
    int len = 0;
    for (int e = h; e >= 0;) { e = (int)(next2[e] >> 32); len++; }
    lds[threadIdx.x] = len;
    __syncthreads();
    for (int off = 1; off < BLK; off <<= 1) {
        int t = ((int)threadIdx.x >= off) ? lds[threadIdx.x - off] : 0;
        __syncthreads();
        lds[threadIdx.x] += t;
        __syncthreads();
    }
    int incl = lds[threadIdx.x];
    if (threadIdx.x == BLK - 1) sbase = atomicAdd(cursor, incl);
    __syncthreads();
    if (!valid) return;
    int pos = sbase + incl - len;
    start[o] = pos;
    endv[o] = pos + len;
    float acc = 0.f;
    for (int e = h; e >= 0;) {
        u64 nd = next2[e];
        unsigned pe = (unsigned)nd;
        acc += ent_w(pe);
        ent[pos++] = pe;
        e = (int)(nd >> 32);
    }
    if (o < Vb) nB[o] = acc;
    else nS[o - Vb] = acc;
}

// ---------------- legacy 4B-node build (used when next2 doesn't fit workspace) ----------------
__global__ void k_link_softmax(const int* __restrict__ osb, const int* __restrict__ oss,
                               int* __restrict__ head, int* __restrict__ next,
                               const float4* __restrict__ u, float4* __restrict__ Q,
                               int Vb) {
    int n = blockIdx.x * BLK + threadIdx.x;
    if (n >= NPIX) return;
    float4 uu = u[n];
    float l0 = -uu.x, l1 = -uu.y, l2 = -uu.z, l3 = -uu.w;
    float m = fmaxf(fmaxf(l0, l1), fmaxf(l2, l3));
    float e0 = expf(l0 - m), e1 = expf(l1 - m), e2 = expf(l2 - m), e3 = expf(l3 - m);
    float inv = 1.0f / (e0 + e1 + e2 + e3);
    Q[n] = make_float4(e0 * inv, e1 * inv, e2 * inv, e3 * inv);
#pragma unroll
    for (int r = 0; r < 6; r++) {
        int o = osb[n * 6 + r];
        int e = n * 6 + r;
        next[e] = atomicExch(&head[o], e);
    }
#pragma unroll
    for (int r = 0; r < 3; r++) {
        int o = Vb + oss[n * 3 + r];
        int e = TOTB + n * 3 + r;
        next[e] = atomicExch(&head[o], e);
    }
}

__global__ void k_compact(const int* __restrict__ head, const int* __restrict__ next,
                          const float* __restrict__ wsb, const float* __restrict__ wss,
                          unsigned* __restrict__ ent, int* __restrict__ start,
                          int* __restrict__ endv,
                          float* __restrict__ nB, float* __restrict__ nS,
                          int* __restrict__ cursor, int V, int Vb) {
    __shared__ int lds[BLK];
    __shared__ int sbase;
    int o = blockIdx.x * BLK + threadIdx.x;
    bool valid = o < V;
    int h = valid ? head[o] : -1;
    int len = 0;
    for (int e = h; e >= 0; e = next[e]) len++;
    lds[threadIdx.x] = len;
    __syncthreads();
    for (int off = 1; off < BLK; off <<= 1) {
        int t = ((int)threadIdx.x >= off) ? lds[threadIdx.x - off] : 0;
        __syncthreads();
        lds[threadIdx.x] += t;
        __syncthreads();
    }
    int incl = lds[threadIdx.x];
    if (threadIdx.x == BLK - 1) sbase = atomicAdd(cursor, incl);
    __syncthreads();
    if (!valid) return;
    int pos = sbase + incl - len;
    start[o] = pos;
    endv[o] = pos + len;
    float acc = 0.f;
    if (o < Vb) {
        for (int e = h; e >= 0; e = next[e]) {
            unsigned n = (unsigned)e / 6u;
            unsigned pe = pack_ent((int)n, wsb[e]);
            acc += ent_w(pe);
            ent[pos++] = pe;
        }
        nB[o] = acc;
    } else {
        for (int e = h; e >= 0; e = next[e]) {
            int ee = e - TOTB;
            unsigned pe = pack_ent(ee / 3, wss[ee]);
            acc += ent_w(pe);
            ent[pos++] = pe;
        }
        nS[o - Vb] = acc;
    }
}

// ---------------- gather-based splat (single concatenated CSR) ----------------
__global__ void k_gather4h_both(const unsigned* __restrict__ ent, const int* __restrict__ start,
                                const int* __restrict__ endv, int V, int Vb,
                                h4* __restrict__ tB, h4* __restrict__ tS,
                                const float4* __restrict__ Q) {
    int i = blockIdx.x * BLK + threadIdx.x;
    if (i >= V) return;
    int s = start[i];
    int e = endv[i];
    float ax = 0.f, ay = 0.f, az = 0.f, aw = 0.f;
    for (int k = s; k < e; k++) {
        unsigned en = ent[k];
        float w = ent_w(en);
        float4 q = Q[ent_pix(en)];
        ax += w * q.x; ay += w * q.y; az += w * q.z; aw += w * q.w;
    }
    h4 h;
    h.x = (_Float16)ax; h.y = (_Float16)ay; h.z = (_Float16)az; h.w = (_Float16)aw;
    if (i < Vb) tB[i] = h;
    else tS[i - Vb] = h;
}

// ---------------- blur (R2-proven 1-vertex/thread versions) ----------------
__global__ void k_blur1(const float* __restrict__ in, float* __restrict__ out,
                        const int* __restrict__ bn, int M) {
    int i = blockIdx.x * BLK + threadIdx.x;
    if (i > M) return;
    if (i == 0) { out[0] = 0.f; return; }
    int n1 = bn[(size_t)(i - 1) * 2 + 0];
    int n2 = bn[(size_t)(i - 1) * 2 + 1];
    out[i] = in[i] + 0.5f * (in[n1] + in[n2]);
}

__global__ void k_blur1_both(const float* __restrict__ inB, float* __restrict__ outB,
                             const int* __restrict__ bnB, int Mb,
                             const float* __restrict__ inS, float* __restrict__ outS,
                             const int* __restrict__ bnS, int Ms) {
    int i = blockIdx.x * BLK + threadIdx.x;
    const float* in; float* out; const int* bn; int M, idx;
    if (i <= Mb) { in = inB; out = outB; bn = bnB; M = Mb; idx = i; }
    else {
        idx = i - (Mb + 1);
        if (idx > Ms) return;
        in = inS; out = outS; bn = bnS; M = Ms;
    }
    if (idx == 0) { out[0] = 0.f; return; }
    int n1 = bn[(size_t)(idx - 1) * 2 + 0];
    int n2 = bn[(size_t)(idx - 1) * 2 + 1];
    out[idx] = in[idx] + 0.5f * (in[n1] + in[n2]);
}

__global__ void k_blur4h(const h4* __restrict__ in, h4* __restrict__ out,
                         const int* __restrict__ bn, int M) {
    int i = blockIdx.x * BLK + threadIdx.x;
    if (i > M) return;
    if (i == 0) { out[0] = h4zero(); return; }
    int n1 = bn[(size_t)(i - 1) * 2 + 0];
    int n2 = bn[(size_t)(i - 1) * 2 + 1];
    h4 a = in[i], b = in[n1], c = in[n2];
    h4 o;
    o.x = (_Float16)((float)a.x + 0.5f * ((float)b.x + (float)c.x));
    o.y = (_Float16)((float)a.y + 0.5f * ((float)b.y + (float)c.y));
    o.z = (_Float16)((float)a.z + 0.5f * ((float)b.z + (float)c.z));
    o.w = (_Float16)((float)a.w + 0.5f * ((float)b.w + (float)c.w));
    out[i] = o;
}

__global__ void k_blur4h_both(const h4* __restrict__ inB, h4* __restrict__ outB,
                              const int* __restrict__ bnB, int Mb,
                              const h4* __restrict__ inS, h4* __restrict__ outS,
                              const int* __restrict__ bnS, int Ms) {
    int i = blockIdx.x * BLK + threadIdx.x;
    const h4* in; h4* out; const int* bn; int M, idx;
    if (i <= Mb) { in = inB; out = outB; bn = bnB; M = Mb; idx = i; }
    else {
        idx = i - (Mb + 1);
        if (idx > Ms) return;
        in = inS; out = outS; bn = bnS; M = Ms;
    }
    if (idx == 0) { out[0] = h4zero(); return; }
    int n1 = bn[(size_t)(idx - 1) * 2 + 0];
    int n2 = bn[(size_t)(idx - 1) * 2 + 1];
    h4 a = in[idx], b = in[n1], c = in[n2];
    h4 o;
    o.x = (_Float16)((float)a.x + 0.5f * ((float)b.x + (float)c.x));
    o.y = (_Float16)((float)a.y + 0.5f * ((float)b.y + (float)c.y));
    o.z = (_Float16)((float)a.z + 0.5f * ((float)b.z + (float)c.z));
    o.w = (_Float16)((float)a.w + 0.5f * ((float)b.w + (float)c.w));
    out[idx] = o;
}

// ---------------- normalizer slice + weight prescale ----------------
__global__ void k_norm_prescale(const float* __restrict__ nTb, const float* __restrict__ wsb,
                                const int* __restrict__ osb,
                                const float* __restrict__ nTs, const float* __restrict__ wss,
                                const int* __restrict__ oss,
                                float* __restrict__ wsbp, float* __restrict__ wssp) {
    int n = blockIdx.x * BLK + threadIdx.x;
    if (n >= NPIX) return;
    float sb = 0.f;
#pragma unroll
    for (int r = 0; r < 6; r++) sb += wsb[n * 6 + r] * nTb[osb[n * 6 + r]];
    float cb = BI_COMPAT * ALPHA_B / (ALPHA_B * sb + 1e-20f);
#pragma unroll
    for (int r = 0; r < 6; r++) wsbp[n * 6 + r] = wsb[n * 6 + r] * cb;
    float ss = 0.f;
#pragma unroll
    for (int r = 0; r < 3; r++) ss += wss[n * 3 + r] * nTs[oss[n * 3 + r]];
    float cs = SP_COMPAT * ALPHA_S / (ALPHA_S * ss + 1e-20f);
#pragma unroll
    for (int r = 0; r < 3; r++) wssp[n * 3 + r] = wss[n * 3 + r] * cs;
}

// ---------------- fused slice + message + softmax ----------------
__global__ void k_slice_combine_h(const float4* __restrict__ u,
                                  const h4* __restrict__ tb, const float* __restrict__ wsbp,
                                  const int* __restrict__ osb,
                                  const h4* __restrict__ ts, const float* __restrict__ wssp,
                                  const int* __restrict__ oss,
                                  float4* __restrict__ Qout) {
    int n = blockIdx.x * BLK + threadIdx.x;
    if (n >= NPIX) return;
    float4 uu = u[n];
    float l0 = -uu.x, l1 = -uu.y, l2 = -uu.z, l3 = -uu.w;
#pragma unroll
    for (int r = 0; r < 6; r++) {
        float w = wsbp[n * 6 + r];
        h4 t = tb[osb[n * 6 + r]];
        l0 += w * (float)t.x; l1 += w * (float)t.y; l2 += w * (float)t.z; l3 += w * (float)t.w;
    }
#pragma unroll
    for (int r = 0; r < 3; r++) {
        float w = wssp[n * 3 + r];
        h4 t = ts[oss[n * 3 + r]];
        l0 += w * (float)t.x; l1 += w * (float)t.y; l2 += w * (float)t.z; l3 += w * (float)t.w;
    }
    float m = fmaxf(fmaxf(l0, l1), fmaxf(l2, l3));
    float e0 = expf(l0 - m), e1 = expf(l1 - m), e2 = expf(l2 - m), e3 = expf(l3 - m);
    float inv = 1.0f / (e0 + e1 + e2 + e3);
    Qout[n] = make_float4(e0 * inv, e1 * inv, e2 * inv, e3 * inv);
}

// ---------------- fallback (fp32 atomic splat path) ----------------
template <int D1>
__global__ void k_splat1(const float* __restrict__ ws, const int* __restrict__ os,
                         float* __restrict__ table) {
    int n = blockIdx.x * BLK + threadIdx.x;
    if (n >= NPIX) return;
#pragma unroll
    for (int r = 0; r < D1; r++) atomicAdd(&table[os[n * D1 + r]], ws[n * D1 + r]);
}

template <int D1>
__global__ void k_splat4(const float4* __restrict__ Q, const float* __restrict__ ws,
                         const int* __restrict__ os, float* __restrict__ table) {
    int n = blockIdx.x * BLK + threadIdx.x;
    if (n >= NPIX) return;
    float4 q = Q[n];
#pragma unroll
    for (int r = 0; r < D1; r++) {
        float w = ws[n * D1 + r];
        int o = os[n * D1 + r];
        float* t = table + 4 * (size_t)o;
        atomicAdd(t + 0, q.x * w);
        atomicAdd(t + 1, q.y * w);
        atomicAdd(t + 2, q.z * w);
        atomicAdd(t + 3, q.w * w);
    }
}

__global__ void k_blur4(const float4* __restrict__ in, float4* __restrict__ out,
                        const int* __restrict__ bn, int M) {
    int i = blockIdx.x * BLK + threadIdx.x;
    if (i > M) return;
    if (i == 0) { out[0] = f4zero(); return; }
    int n1 = bn[(size_t)(i - 1) * 2 + 0];
    int n2 = bn[(size_t)(i - 1) * 2 + 1];
    float4 a = in[i], b = in[n1], c = in[n2];
    out[i] = make_float4(a.x + 0.5f * (b.x + c.x), a.y + 0.5f * (b.y + c.y),
                         a.z + 0.5f * (b.z + c.z), a.w + 0.5f * (b.w + c.w));
}

template <int D1>
__global__ void k_norm_slice(const float* __restrict__ table, const float* __restrict__ ws,
                             const int* __restrict__ os, float alpha,
                             float* __restrict__ inv_out) {
    int n = blockIdx.x * BLK + threadIdx.x;
    if (n >= NPIX) return;
    float s = 0.f;
#pragma unroll
    for (int r = 0; r < D1; r++) s += ws[n * D1 + r] * table[os[n * D1 + r]];
    inv_out[n] = 1.0f / (alpha * s + 1e-20f);
}

__global__ void k_slice_combine(const float4* __restrict__ u,
                                const float4* __restrict__ tb, const float* __restrict__ wsb,
                                const int* __restrict__ osb,
                                const float4* __restrict__ ts, const float* __restrict__ wss,
                                const int* __restrict__ oss,
                                const float* __restrict__ inv_nb,
                                const float* __restrict__ inv_ns,
                                float4* __restrict__ Qout) {
    int n = blockIdx.x * BLK + threadIdx.x;
    if (n >= NPIX) return;
    float4 ab = f4zero();
#pragma unroll
    for (int r = 0; r < 6; r++) {
        float w = wsb[n * 6 + r];
        float4 t = tb[osb[n * 6 + r]];
        ab.x += w * t.x; ab.y += w * t.y; ab.z += w * t.z; ab.w += w * t.w;
    }
    float4 as = f4zero();
#pragma unroll
    for (int r = 0; r < 3; r++) {
        float w = wss[n * 3 + r];
        float4 t = ts[oss[n * 3 + r]];
        as.x += w * t.x; as.y += w * t.y; as.z += w * t.z; as.w += w * t.w;
    }
    float cb = BI_COMPAT * ALPHA_B * inv_nb[n];
    float cs = SP_COMPAT * ALPHA_S * inv_ns[n];
    float4 uu = u[n];
    float l0 = -uu.x + cb * ab.x + cs * as.x;
    float l1 = -uu.y + cb * ab.y + cs * as.y;
    float l2 = -uu.z + cb * ab.z + cs * as.z;
    float l3 = -uu.w + cb * ab.w + cs * as.w;
    float m = fmaxf(fmaxf(l0, l1), fmaxf(l2, l3));
    float e0 = expf(l0 - m), e1 = expf(l1 - m), e2 = expf(l2 - m), e3 = expf(l3 - m);
    float inv = 1.0f / (e0 + e1 + e2 + e3);
    Qout[n] = make_float4(e0 * inv, e1 * inv, e2 * inv, e3 * inv);
}

extern "C" void kernel_launch(void* const* d_in, const int* in_sizes, int n_in,
                              void* d_out, int out_size, void* d_ws, size_t ws_size,
                              hipStream_t stream) {
    const float* unary = (const float*)d_in[0];
    const float* wsb   = (const float*)d_in[1];
    const int*   osb   = (const int*)d_in[2];
    const int*   bnb   = (const int*)d_in[3];
    const float* wss   = (const float*)d_in[5];
    const int*   oss   = (const int*)d_in[6];
    const int*   bns   = (const int*)d_in[7];
    const int Mb = in_sizes[3] / 12;   // bn_b is (6, Mb, 2)
    const int Ms = in_sizes[7] / 6;    // bn_s is (3, Ms, 2)
    const int Vb = Mb + 1, Vs = Ms + 1;
    const int V = Vb + Vs;

    float* Q = (float*)d_out;  // N x 4, final value IS the output

    char* p = (char*)d_ws;
    auto alloc = [&](size_t nbytes) -> void* {
        void* r = (void*)p;
        p += (nbytes + 15) & ~(size_t)15;
        return r;
    };
    // ---- aliasable region (4B-fallback only): everything here is first WRITTEN
    // after k_compact. wsbp/wssp: by k_norm_prescale; tA*/tB*: by iteration-1;
    // nBb/nBs: by first norm blur. wsbp+wssp alone = TOTE*4 -> next4 always fits.
    char* region0 = p;
    float* wsbp = (float*)alloc((size_t)NPIX * 6 * 4);
    float* wssp = (float*)alloc((size_t)NPIX * 3 * 4);
    h4*   tAb  = (h4*)alloc((size_t)Vb * 8);
    h4*   tBb  = (h4*)alloc((size_t)Vb * 8);
    h4*   tAs  = (h4*)alloc((size_t)Vs * 8);
    h4*   tBs  = (h4*)alloc((size_t)Vs * 8);
    float* nBb = (float*)alloc((size_t)Vb * 4);
    float* nBs = (float*)alloc((size_t)Vs * 4);
    // ---- non-aliased (live across build) ----
    float* nAb = (float*)alloc((size_t)Vb * 4);   // written by k_compact*
    float* nAs = (float*)alloc((size_t)Vs * 4);
    int*  start = (int*)alloc((size_t)V * 4);
    int*  endv  = (int*)alloc((size_t)V * 4);
    int*  head  = (int*)alloc((size_t)V * 4);
    unsigned* ent = (unsigned*)alloc((size_t)TOTE * 4);
    int*  cursor = (int*)alloc(16);
    size_t base_need = (size_t)(p - (char*)d_ws);
    // dedicated 8B node array at the TAIL (no alias constraints at all)
    u64*  next2 = (u64*)alloc((size_t)TOTE * 8);
    size_t need8 = (size_t)(p - (char*)d_ws);
    bool use8 = need8 <= ws_size;                 // preferred: wave-aggregated payload nodes
    bool use_gather = base_need <= ws_size;       // 4B path: next4 aliases region0
    int*  next4 = (int*)region0;

    dim3 blk(BLK);
    dim3 gN((NPIX + BLK - 1) / BLK);
    dim3 gVb((Vb + BLK - 1) / BLK);
    dim3 gV((V + BLK - 1) / BLK);
    dim3 gVBS((Vb + Vs + 1 + BLK - 1) / BLK);

    if (use_gather) {
        // ---- build CSR via (wave-aggregated) linked-list inversion + compaction ----
        hipMemsetAsync(head, 0xFF, (size_t)V * 4, stream);  // -1 sentinel
        hipMemsetAsync(cursor, 0, 16, stream);
        if (use8) {
            k_link2_softmax<<<gN, blk, 0, stream>>>(osb, wsb, oss, wss, head, next2,
                                                    (const float4*)unary, (float4*)Q, Vb);
            k_compact2<<<gV, blk, 0, stream>>>(head, next2, ent, start, endv,
                                               nAb, nAs, cursor, V, Vb);
        } else {
            k_link_softmax<<<gN, blk, 0, stream>>>(osb, oss, head, next4,
                                                   (const float4*)unary, (float4*)Q, Vb);
            k_compact<<<gV, blk, 0, stream>>>(head, next4, wsb, wss, ent, start, endv,
                                              nAb, nAs, cursor, V, Vb);
        }

        // ---- normalizer blur chain (C=1, fp32), then prescale slice weights ----
        {
            float* a = nAb; float* b = nBb;
            float* as_ = nAs; float* bs_ = nBs;
            for (int j = 0; j < 3; j++) {
                k_blur1_both<<<gVBS, blk, 0, stream>>>(a, b, bnb + (size_t)j * Mb * 2, Mb,
                                                       as_, bs_, bns + (size_t)j * Ms * 2, Ms);
                float* t = a; a = b; b = t;
                t = as_; as_ = bs_; bs_ = t;
            }
            for (int j = 3; j < 6; j++) {
                k_blur1<<<gVb, blk, 0, stream>>>(a, b, bnb + (size_t)j * Mb * 2, Mb);
                float* t = a; a = b; b = t;
            }
            // bilateral final in a (= nAb), spatial final in as_ (= nBs)
            k_norm_prescale<<<gN, blk, 0, stream>>>(a, wsb, osb, as_, wss, oss, wsbp, wssp);
        }

        // ---- 10 mean-field iterations ----
        for (int it = 0; it < 10; it++) {
            k_gather4h_both<<<gV, blk, 0, stream>>>(ent, start, endv, V, Vb, tAb, tAs,
                                                    (const float4*)Q);
            h4* a = tAb; h4* b = tBb;
            h4* as_ = tAs; h4* bs_ = tBs;
            for (int j = 0; j < 3; j++) {
                k_blur4h_both<<<gVBS, blk, 0, stream>>>(a, b, bnb + (size_t)j * Mb * 2, Mb,
                                                        as_, bs_, bns + (size_t)j * Ms * 2, Ms);
                h4* t = a; a = b; b = t;
                t = as_; as_ = bs_; bs_ = t;
            }
            for (int j = 3; j < 6; j++) {
                k_blur4h<<<gVb, blk, 0, stream>>>(a, b, bnb + (size_t)j * Mb * 2, Mb);
                h4* t = a; a = b; b = t;
            }
            // bilateral final in a (= tAb), spatial final in as_ (= tBs)
            k_slice_combine_h<<<gN, blk, 0, stream>>>((const float4*)unary,
                                                      a, wsbp, osb, as_, wssp, oss,
                                                      (float4*)Q);
        }
    } else {
        // ---- fallback: fp32 atomic splat path ----
        char* q = (char*)d_ws;
        auto alloc2 = [&](size_t nbytes) -> void* {
            void* r = (void*)q;
            q += (nbytes + 15) & ~(size_t)15;
            return r;
        };
        float* fAb = (float*)alloc2((size_t)Vb * 4 * sizeof(float));
        float* fBb = (float*)alloc2((size_t)Vb * 4 * sizeof(float));
        float* fAs = (float*)alloc2((size_t)Vs * 4 * sizeof(float));
        float* fBs = (float*)alloc2((size_t)Vs * 4 * sizeof(float));
        float* inv_nb = (float*)alloc2(NPIX * sizeof(float));
        float* inv_ns = (float*)alloc2(NPIX * sizeof(float));
        dim3 gMb((Mb + 1 + BLK - 1) / BLK);
        dim3 gMs((Ms + 1 + BLK - 1) / BLK);

        hipMemsetAsync(fAb, 0, (size_t)Vb * sizeof(float), stream);
        k_splat1<6><<<gN, blk, 0, stream>>>(wsb, osb, fAb);
        {
            float* a = fAb; float* b = fBb;
            for (int j = 0; j < 6; j++) {
                k_blur1<<<gMb, blk, 0, stream>>>(a, b, bnb + (size_t)j * Mb * 2, Mb);
                float* t = a; a = b; b = t;
            }
            k_norm_slice<6><<<gN, blk, 0, stream>>>(a, wsb, osb, ALPHA_B, inv_nb);
        }
        hipMemsetAsync(fAs, 0, (size_t)Vs * sizeof(float), stream);
        k_splat1<3><<<gN, blk, 0, stream>>>(wss, oss, fAs);
        {
            float* a = fAs; float* b = fBs;
            for (int j = 0; j < 3; j++) {
                k_blur1<<<gMs, blk, 0, stream>>>(a, b, bns + (size_t)j * Ms * 2, Ms);
                float* t = a; a = b; b = t;
            }
            k_norm_slice<3><<<gN, blk, 0, stream>>>(a, wss, oss, ALPHA_S, inv_ns);
        }
        k_softmax_init<<<gN, blk, 0, stream>>>((const float4*)unary, (float4*)Q);
        for (int it = 0; it < 10; it++) {
            hipMemsetAsync(fAb, 0, (size_t)Vb * 4 * sizeof(float), stream);
            k_splat4<6><<<gN, blk, 0, stream>>>((const float4*)Q, wsb, osb, fAb);
            float* a = fAb; float* b = fBb;
            for (int j = 0; j < 6; j++) {
                k_blur4<<<gMb, blk, 0, stream>>>((const float4*)a, (float4*)b,
                                                 bnb + (size_t)j * Mb * 2, Mb);
                float* t = a; a = b; b = t;
            }
            float* finb = a;
            hipMemsetAsync(fAs, 0, (size_t)Vs * 4 * sizeof(float), stream);
            k_splat4<3><<<gN, blk, 0, stream>>>((const float4*)Q, wss, oss, fAs);
            float* as_ = fAs; float* bs_ = fBs;
            for (int j = 0; j < 3; j++) {
                k_blur4<<<gMs, blk, 0, stream>>>((const float4*)as_, (float4*)bs_,
                                                 bns + (size_t)j * Ms * 2, Ms);
                float* t = as_; as_ = bs_; bs_ = t;
            }
            float* fins = as_;
            k_slice_combine<<<gN, blk, 0, stream>>>((const float4*)unary,
                                                    (const float4*)finb, wsb, osb,
                                                    (const float4*)fins, wss, oss,
                                                    inv_nb, inv_ns, (float4*)Q);
        }
    }
}